// Round 1
// baseline (3638.972 us; speedup 1.0000x reference)
//
#include <hip/hip_runtime.h>

#define EPS_BN 1e-5f

// ---------------- preprocessing ----------------

__global__ void k_deg(const int* __restrict__ src, float* __restrict__ deg, int E) {
  int e = blockIdx.x * 256 + threadIdx.x;
  if (e < E) atomicAdd(&deg[src[e]], 1.0f);
}

__global__ void k_dinv(float* __restrict__ deg, int N) {
  int i = blockIdx.x * 256 + threadIdx.x;
  if (i < N) { float d = deg[i]; deg[i] = d > 0.f ? 1.0f / sqrtf(d) : 0.f; }
}

__global__ void k_hist(const int* __restrict__ dst, int* __restrict__ hist, int E) {
  int e = blockIdx.x * 256 + threadIdx.x;
  if (e < E) atomicAdd(&hist[dst[e]], 1);
}

// single-block exclusive scan over N bins (1024 threads)
__global__ void k_scan(const int* __restrict__ hist, int* __restrict__ offs, int N, int E) {
  __shared__ int lds[1024];
  int t = threadIdx.x;
  int chunk = (N + 1023) >> 10;
  int lo = t * chunk; if (lo > N) lo = N;
  int hi = lo + chunk; if (hi > N) hi = N;
  int s = 0;
  for (int i = lo; i < hi; i++) s += hist[i];
  lds[t] = s; __syncthreads();
  for (int off = 1; off < 1024; off <<= 1) {
    int v = (t >= off) ? lds[t - off] : 0;
    __syncthreads();
    lds[t] += v;
    __syncthreads();
  }
  int run = lds[t] - s;  // exclusive prefix
  for (int i = lo; i < hi; i++) { offs[i] = run; run += hist[i]; }
  if (t == 0) offs[N] = E;
}

__global__ void k_scatter(const int* __restrict__ src, const int* __restrict__ dst,
                          const float* __restrict__ dinv, const int* __restrict__ offs,
                          int* __restrict__ cursor, int* __restrict__ ssrc,
                          float* __restrict__ sew, int E) {
  int e = blockIdx.x * 256 + threadIdx.x;
  if (e >= E) return;
  int s = src[e], d = dst[e];
  int pos = offs[d] + atomicAdd(&cursor[d], 1);
  ssrc[pos] = s;
  sew[pos] = -dinv[s] * dinv[d];
}

// ---------------- propagation (CSR by dst, no atomics) ----------------
// out[n,f] = (recur ? 2*sum - old[n,f] : sum),  sum = sum_e ew[e]*gf[ssrc[e],f]
// wave-per-node, lane = feature (F=64)
__global__ void k_prop64(const float* __restrict__ gf, const float* __restrict__ oldv,
                         float* __restrict__ outv, const int* __restrict__ offs,
                         const int* __restrict__ ssrc, const float* __restrict__ sew,
                         int N, int recur) {
  int wid = (blockIdx.x * 256 + threadIdx.x) >> 6;
  int lane = threadIdx.x & 63;
  if (wid >= N) return;
  int r0 = offs[wid], r1 = offs[wid + 1];
  float acc = 0.f;
  for (int e = r0; e < r1; e++) {
    int s = ssrc[e];
    float w = sew[e];
    acc += w * gf[s * 64 + lane];
  }
  int idx = wid * 64 + lane;
  if (recur) outv[idx] = 2.f * acc - oldv[idx];
  else       outv[idx] = acc;
}

// F=3 variant: thread-per-node
__global__ void k_prop3(const float* __restrict__ gf, const float* __restrict__ oldv,
                        float* __restrict__ outv, const int* __restrict__ offs,
                        const int* __restrict__ ssrc, const float* __restrict__ sew,
                        int N, int recur) {
  int n = blockIdx.x * 256 + threadIdx.x;
  if (n >= N) return;
  int r0 = offs[n], r1 = offs[n + 1];
  float a0 = 0.f, a1 = 0.f, a2 = 0.f;
  for (int e = r0; e < r1; e++) {
    int s = ssrc[e];
    float w = sew[e];
    a0 += w * gf[s * 3 + 0];
    a1 += w * gf[s * 3 + 1];
    a2 += w * gf[s * 3 + 2];
  }
  if (recur) {
    a0 = 2.f * a0 - oldv[n * 3 + 0];
    a1 = 2.f * a1 - oldv[n * 3 + 1];
    a2 = 2.f * a2 - oldv[n * 3 + 2];
  }
  outv[n * 3 + 0] = a0;
  outv[n * 3 + 1] = a1;
  outv[n * 3 + 2] = a2;
}

// ---------------- combine: H = [bias or H] + TxA@WA (+ TxB@WB) ----------------
template <int FOUT>
__global__ void k_combine(float* __restrict__ H, const float* __restrict__ TxA,
                          const float* __restrict__ WA, const float* __restrict__ TxB,
                          const float* __restrict__ WB, const float* __restrict__ bias,
                          int N, int Fin, int mode /*0=init(bias), 1=accumulate*/) {
  extern __shared__ float lds[];
  float* wa = lds;
  float* wb = lds + Fin * FOUT;
  int tid = threadIdx.x;
  for (int i = tid; i < Fin * FOUT; i += 256) wa[i] = WA[i];
  if (TxB) for (int i = tid; i < Fin * FOUT; i += 256) wb[i] = WB[i];
  __syncthreads();
  const int NPB = 256 / FOUT;
  int n = blockIdx.x * NPB + tid / FOUT;
  int j = tid % FOUT;
  if (n >= N) return;
  float acc = mode ? H[n * FOUT + j] : bias[j];
  for (int i = 0; i < Fin; i++) acc += TxA[n * Fin + i] * wa[i * FOUT + j];
  if (TxB) for (int i = 0; i < Fin; i++) acc += TxB[n * Fin + i] * wb[i * FOUT + j];
  H[n * FOUT + j] = acc;
}

// ---------------- LeakyReLU + BN stats (in-place lrelu, partial sums) ----------------
__global__ void k_bnstats(float* __restrict__ H, float* __restrict__ gsum,
                          float* __restrict__ gsum2, int N) {
  __shared__ float ls[256], ls2[256];
  int t = threadIdx.x;
  int f = t & 63, r = t >> 6;
  float s = 0.f, s2 = 0.f;
  for (int n = blockIdx.x * 4 + r; n < N; n += gridDim.x * 4) {
    float v = H[n * 64 + f];
    v = v >= 0.f ? v : 0.01f * v;
    H[n * 64 + f] = v;
    s += v; s2 += v * v;
  }
  ls[t] = s; ls2[t] = s2;
  __syncthreads();
  if (t < 64) {
    float a = ls[t] + ls[t + 64] + ls[t + 128] + ls[t + 192];
    float b = ls2[t] + ls2[t + 64] + ls2[t + 128] + ls2[t + 192];
    atomicAdd(&gsum[t], a);
    atomicAdd(&gsum2[t], b);
  }
}

__global__ void k_bnfinal(const float* __restrict__ gsum, const float* __restrict__ gsum2,
                          const float* __restrict__ g, const float* __restrict__ bt,
                          float* __restrict__ ab, float Ninv) {
  int f = threadIdx.x;
  if (f < 64) {
    float mu = gsum[f] * Ninv;
    float var = gsum2[f] * Ninv - mu * mu;
    float a = g[f] / sqrtf(var + EPS_BN);
    ab[f] = a;
    ab[64 + f] = bt[f] - mu * a;
  }
}

__global__ void k_bnapply(const float* __restrict__ H, const float* __restrict__ ab,
                          float* __restrict__ A, int total) {
  int i = blockIdx.x * 256 + threadIdx.x;
  if (i < total) {
    int f = i & 63;
    A[i] = H[i] * ab[f] + ab[64 + f];
  }
}

// ---------------- row L2 normalize (F=32) ----------------
__global__ void k_norm(float* __restrict__ H, int N) {
  int idx = blockIdx.x * 256 + threadIdx.x;
  int n = idx >> 5, f = idx & 31;
  if (n >= N) return;
  float v = H[n * 32 + f];
  float s = v * v;
  for (int off = 16; off; off >>= 1) s += __shfl_xor(s, off, 32);
  float nrm = sqrtf(s);
  nrm = fmaxf(nrm, 1e-12f);
  H[n * 32 + f] = v / nrm;
}

// ---------------- pooling ----------------
__device__ __forceinline__ unsigned fkey(float x) {
  unsigned u = __float_as_uint(x);
  return (u & 0x80000000u) ? ~u : (u | 0x80000000u);
}
__device__ __forceinline__ float fdec(unsigned u) {
  return (u & 0x80000000u) ? __uint_as_float(u & 0x7FFFFFFFu) : __uint_as_float(~u);
}

__global__ void k_pool(const float* __restrict__ H, const int* __restrict__ batch,
                       float* __restrict__ psum, unsigned* __restrict__ pmax,
                       unsigned* __restrict__ pmin, float* __restrict__ pcnt, int N) {
  int idx = blockIdx.x * 256 + threadIdx.x;
  int n = idx >> 5, f = idx & 31;
  if (n >= N) return;
  int g = batch[n];
  float v = H[n * 32 + f];
  atomicAdd(&psum[g * 32 + f], v);
  atomicMax(&pmax[g * 32 + f], fkey(v));
  atomicMin(&pmin[g * 32 + f], fkey(v));
  if (f == 0) atomicAdd(&pcnt[g], 1.0f);
}

__global__ void k_poolfin(const float* __restrict__ psum, const unsigned* __restrict__ pmax,
                          const unsigned* __restrict__ pmin, const float* __restrict__ pcnt,
                          float* __restrict__ out) {
  int g = blockIdx.x, f = threadIdx.x;  // 64 x 32
  float s = psum[g * 32 + f];
  float c = fmaxf(pcnt[g], 1.0f);
  out[g * 128 + f] = s / c;
  out[g * 128 + 32 + f] = fdec(pmax[g * 32 + f]);
  out[g * 128 + 64 + f] = fdec(pmin[g * 32 + f]);
  out[g * 128 + 96 + f] = s;
}

// ---------------- host ----------------

extern "C" void kernel_launch(void* const* d_in, const int* in_sizes, int n_in,
                              void* d_out, int out_size, void* d_ws, size_t ws_size,
                              hipStream_t stream) {
  const float* x   = (const float*)d_in[0];
  const int*   ei  = (const int*)d_in[1];
  const int*   bat = (const int*)d_in[2];
  const float* W1  = (const float*)d_in[3];  const float* bc1 = (const float*)d_in[4];
  const float* W2  = (const float*)d_in[5];  const float* bc2 = (const float*)d_in[6];
  const float* W3  = (const float*)d_in[7];  const float* bc3 = (const float*)d_in[8];
  const float* W4  = (const float*)d_in[9];  const float* bc4 = (const float*)d_in[10];
  const float* g1  = (const float*)d_in[11]; const float* bt1 = (const float*)d_in[12];
  const float* g2  = (const float*)d_in[13]; const float* bt2 = (const float*)d_in[14];
  const float* g3  = (const float*)d_in[15]; const float* bt3 = (const float*)d_in[16];

  const int N = in_sizes[0] / 3;
  const int E = in_sizes[1] / 2;
  const int* src = ei;
  const int* dst = ei + E;

  // ---- workspace layout (float-element granularity, 64-elt aligned) ----
  float* base = (float*)d_ws;
  size_t o = 0;
  auto alloc = [&](size_t n) -> float* {
    float* p = base + o;
    o += (n + 63) & ~(size_t)63;
    return p;
  };
  // zeroed region (contiguous from d_ws start):
  float* deg    = alloc(N);           // becomes dinv in-place
  int*   hist   = (int*)alloc(N);
  int*   cursor = (int*)alloc(N);
  float* bnacc  = alloc(6 * 64);      // [layer][sum|sum2][64] -> 3 pairs
  float* psum   = alloc(64 * 32);
  float* pcnt   = alloc(64);
  unsigned* pmax = (unsigned*)alloc(64 * 32);
  size_t zero_elems = o;
  // 0xFF region:
  unsigned* pmin = (unsigned*)alloc(64 * 32);
  // uninitialized (fully overwritten before read):
  int*   offs = (int*)alloc(N + 1);
  int*   ssrc = (int*)alloc(E);
  float* sew  = alloc(E);
  float* ab   = alloc(128);
  float* A    = alloc((size_t)N * 64);
  float* B    = alloc((size_t)N * 64);
  float* H    = alloc((size_t)N * 64);

  hipMemsetAsync(d_ws, 0, zero_elems * sizeof(float), stream);
  hipMemsetAsync(pmin, 0xFF, 64 * 32 * sizeof(unsigned), stream);

  const int EB = (E + 255) / 256;
  const int NB = (N + 255) / 256;

  // ---- build dinv + CSR(dst) ----
  k_deg<<<EB, 256, 0, stream>>>(src, deg, E);
  k_dinv<<<NB, 256, 0, stream>>>(deg, N);
  k_hist<<<EB, 256, 0, stream>>>(dst, hist, E);
  k_scan<<<1, 1024, 0, stream>>>(hist, offs, N, E);
  k_scatter<<<EB, 256, 0, stream>>>(src, dst, deg, offs, cursor, ssrc, sew, E);

  const int PB64 = (N * 64 + 255) / 256;  // wave-per-node blocks
  const int CB64 = (N + 3) / 4;
  const int CB32 = (N + 7) / 8;

  auto comb64 = [&](const float* TxA, const float* WA, const float* TxB, const float* WB,
                    const float* bias, int Fin, int mode) {
    size_t sh = (size_t)(TxB ? 2 : 1) * Fin * 64 * sizeof(float);
    k_combine<64><<<CB64, 256, sh, stream>>>(H, TxA, WA, TxB, WB, bias, N, Fin, mode);
  };
  auto comb32 = [&](const float* TxA, const float* WA, const float* TxB, const float* WB,
                    const float* bias, int Fin, int mode) {
    size_t sh = (size_t)(TxB ? 2 : 1) * Fin * 32 * sizeof(float);
    k_combine<32><<<CB32, 256, sh, stream>>>(H, TxA, WA, TxB, WB, bias, N, Fin, mode);
  };

  // ---- layer 1: Fin=3 -> 64 ----
  {
    const float* W = W1;
    k_prop3<<<NB, 256, 0, stream>>>(x, nullptr, B, offs, ssrc, sew, N, 0);        // B = L x
    comb64(x, W + 0 * 192, B, W + 1 * 192, bc1, 3, 0);                            // H = b + xW0 + BW1
    k_prop3<<<NB, 256, 0, stream>>>(B, x, A, offs, ssrc, sew, N, 1);              // A = 2LB - x
    comb64(A, W + 2 * 192, nullptr, nullptr, nullptr, 3, 1);                      // H += AW2
    k_prop3<<<NB, 256, 0, stream>>>(A, B, B, offs, ssrc, sew, N, 1);              // B = 2LA - B
    comb64(B, W + 3 * 192, nullptr, nullptr, nullptr, 3, 1);                      // H += BW3
    k_bnstats<<<256, 256, 0, stream>>>(H, bnacc + 0, bnacc + 64, N);
    k_bnfinal<<<1, 64, 0, stream>>>(bnacc + 0, bnacc + 64, g1, bt1, ab, 1.0f / N);
    k_bnapply<<<PB64, 256, 0, stream>>>(H, ab, A, N * 64);                        // A = Tx0 of layer2
  }

  // ---- layers 2 & 3: 64 -> 64 ----
  const float* Ws[2] = {W2, W3};
  const float* bs[2] = {bc2, bc3};
  const float* gs[2] = {g2, g3};
  const float* bts[2] = {bt2, bt3};
  for (int L = 0; L < 2; L++) {
    const float* W = Ws[L];
    k_prop64<<<PB64, 256, 0, stream>>>(A, nullptr, B, offs, ssrc, sew, N, 0);     // B = LA
    comb64(A, W + 0 * 4096, B, W + 1 * 4096, bs[L], 64, 0);
    k_prop64<<<PB64, 256, 0, stream>>>(B, A, A, offs, ssrc, sew, N, 1);           // A = 2LB - A
    comb64(A, W + 2 * 4096, nullptr, nullptr, nullptr, 64, 1);
    k_prop64<<<PB64, 256, 0, stream>>>(A, B, B, offs, ssrc, sew, N, 1);           // B = 2LA - B
    comb64(B, W + 3 * 4096, nullptr, nullptr, nullptr, 64, 1);
    k_bnstats<<<256, 256, 0, stream>>>(H, bnacc + (L + 1) * 128, bnacc + (L + 1) * 128 + 64, N);
    k_bnfinal<<<1, 64, 0, stream>>>(bnacc + (L + 1) * 128, bnacc + (L + 1) * 128 + 64,
                                    gs[L], bts[L], ab, 1.0f / N);
    k_bnapply<<<PB64, 256, 0, stream>>>(H, ab, A, N * 64);
  }

  // ---- layer 4: 64 -> 32 ----
  {
    const float* W = W4;
    k_prop64<<<PB64, 256, 0, stream>>>(A, nullptr, B, offs, ssrc, sew, N, 0);
    comb32(A, W + 0 * 2048, B, W + 1 * 2048, bc4, 64, 0);
    k_prop64<<<PB64, 256, 0, stream>>>(B, A, A, offs, ssrc, sew, N, 1);
    comb32(A, W + 2 * 2048, nullptr, nullptr, nullptr, 64, 1);
    k_prop64<<<PB64, 256, 0, stream>>>(A, B, B, offs, ssrc, sew, N, 1);
    comb32(B, W + 3 * 2048, nullptr, nullptr, nullptr, 64, 1);
  }

  // ---- normalize + pool ----
  const int RB32 = (N * 32 + 255) / 256;
  k_norm<<<RB32, 256, 0, stream>>>(H, N);
  k_pool<<<RB32, 256, 0, stream>>>(H, bat, psum, pmax, pmin, pcnt, N);
  k_poolfin<<<64, 32, 0, stream>>>(psum, pmax, pmin, pcnt, (float*)d_out);
}

// Round 2
// 2783.024 us; speedup vs baseline: 1.3076x; 1.3076x over previous
//
#include <hip/hip_runtime.h>

#define EPS_BN 1e-5f

// ---------------- preprocessing ----------------

__global__ void k_deg(const int* __restrict__ src, float* __restrict__ deg, int E) {
  int e = blockIdx.x * 256 + threadIdx.x;
  if (e < E) atomicAdd(&deg[src[e]], 1.0f);
}

__global__ void k_dinv(float* __restrict__ deg, int N) {
  int i = blockIdx.x * 256 + threadIdx.x;
  if (i < N) { float d = deg[i]; deg[i] = d > 0.f ? 1.0f / sqrtf(d) : 0.f; }
}

__global__ void k_hist(const int* __restrict__ dst, int* __restrict__ hist, int E) {
  int e = blockIdx.x * 256 + threadIdx.x;
  if (e < E) atomicAdd(&hist[dst[e]], 1);
}

// single-block exclusive scan over N bins (1024 threads)
__global__ void k_scan(const int* __restrict__ hist, int* __restrict__ offs, int N, int E) {
  __shared__ int lds[1024];
  int t = threadIdx.x;
  int chunk = (N + 1023) >> 10;
  int lo = t * chunk; if (lo > N) lo = N;
  int hi = lo + chunk; if (hi > N) hi = N;
  int s = 0;
  for (int i = lo; i < hi; i++) s += hist[i];
  lds[t] = s; __syncthreads();
  for (int off = 1; off < 1024; off <<= 1) {
    int v = (t >= off) ? lds[t - off] : 0;
    __syncthreads();
    lds[t] += v;
    __syncthreads();
  }
  int run = lds[t] - s;  // exclusive prefix
  for (int i = lo; i < hi; i++) { offs[i] = run; run += hist[i]; }
  if (t == 0) offs[N] = E;
}

__global__ void k_scatter(const int* __restrict__ src, const int* __restrict__ dst,
                          const float* __restrict__ dinv, const int* __restrict__ offs,
                          int* __restrict__ cursor, int* __restrict__ ssrc,
                          float* __restrict__ sew, int E) {
  int e = blockIdx.x * 256 + threadIdx.x;
  if (e >= E) return;
  int s = src[e], d = dst[e];
  int pos = offs[d] + atomicAdd(&cursor[d], 1);
  ssrc[pos] = s;
  sew[pos] = -dinv[s] * dinv[d];
}

// ---------------- propagation (CSR by dst, no atomics) ----------------
// out[n,f] = (recur ? 2*sum - old[n,f] : sum),  sum = sum_e ew[e]*gf[ssrc[e],f]
// wave-per-node, lane = feature (F=64)
__global__ void k_prop64(const float* __restrict__ gf, const float* __restrict__ oldv,
                         float* __restrict__ outv, const int* __restrict__ offs,
                         const int* __restrict__ ssrc, const float* __restrict__ sew,
                         int N, int recur) {
  int wid = (blockIdx.x * 256 + threadIdx.x) >> 6;
  int lane = threadIdx.x & 63;
  if (wid >= N) return;
  int r0 = offs[wid], r1 = offs[wid + 1];
  float acc = 0.f;
  for (int e = r0; e < r1; e++) {
    int s = ssrc[e];
    float w = sew[e];
    acc += w * gf[s * 64 + lane];
  }
  int idx = wid * 64 + lane;
  if (recur) outv[idx] = 2.f * acc - oldv[idx];
  else       outv[idx] = acc;
}

// F=3 variant: thread-per-node
__global__ void k_prop3(const float* __restrict__ gf, const float* __restrict__ oldv,
                        float* __restrict__ outv, const int* __restrict__ offs,
                        const int* __restrict__ ssrc, const float* __restrict__ sew,
                        int N, int recur) {
  int n = blockIdx.x * 256 + threadIdx.x;
  if (n >= N) return;
  int r0 = offs[n], r1 = offs[n + 1];
  float a0 = 0.f, a1 = 0.f, a2 = 0.f;
  for (int e = r0; e < r1; e++) {
    int s = ssrc[e];
    float w = sew[e];
    a0 += w * gf[s * 3 + 0];
    a1 += w * gf[s * 3 + 1];
    a2 += w * gf[s * 3 + 2];
  }
  if (recur) {
    a0 = 2.f * a0 - oldv[n * 3 + 0];
    a1 = 2.f * a1 - oldv[n * 3 + 1];
    a2 = 2.f * a2 - oldv[n * 3 + 2];
  }
  outv[n * 3 + 0] = a0;
  outv[n * 3 + 1] = a1;
  outv[n * 3 + 2] = a2;
}

// ---------------- combine: H = [bias or H] + TxA@WA (+ TxB@WB) ----------------
template <int FOUT>
__global__ void k_combine(float* __restrict__ H, const float* __restrict__ TxA,
                          const float* __restrict__ WA, const float* __restrict__ TxB,
                          const float* __restrict__ WB, const float* __restrict__ bias,
                          int N, int Fin, int mode /*0=init(bias), 1=accumulate*/) {
  extern __shared__ float lds[];
  float* wa = lds;
  float* wb = lds + Fin * FOUT;
  int tid = threadIdx.x;
  for (int i = tid; i < Fin * FOUT; i += 256) wa[i] = WA[i];
  if (TxB) for (int i = tid; i < Fin * FOUT; i += 256) wb[i] = WB[i];
  __syncthreads();
  const int NPB = 256 / FOUT;
  int n = blockIdx.x * NPB + tid / FOUT;
  int j = tid % FOUT;
  if (n >= N) return;
  float acc = mode ? H[n * FOUT + j] : bias[j];
  for (int i = 0; i < Fin; i++) acc += TxA[n * Fin + i] * wa[i * FOUT + j];
  if (TxB) for (int i = 0; i < Fin; i++) acc += TxB[n * Fin + i] * wb[i * FOUT + j];
  H[n * FOUT + j] = acc;
}

// ---------------- LeakyReLU + BN stats (in-place lrelu, partial sums) ----------------
__global__ void k_bnstats(float* __restrict__ H, float* __restrict__ gsum,
                          float* __restrict__ gsum2, int N) {
  __shared__ float ls[256], ls2[256];
  int t = threadIdx.x;
  int f = t & 63, r = t >> 6;
  float s = 0.f, s2 = 0.f;
  for (int n = blockIdx.x * 4 + r; n < N; n += gridDim.x * 4) {
    float v = H[n * 64 + f];
    v = v >= 0.f ? v : 0.01f * v;
    H[n * 64 + f] = v;
    s += v; s2 += v * v;
  }
  ls[t] = s; ls2[t] = s2;
  __syncthreads();
  if (t < 64) {
    float a = ls[t] + ls[t + 64] + ls[t + 128] + ls[t + 192];
    float b = ls2[t] + ls2[t + 64] + ls2[t + 128] + ls2[t + 192];
    atomicAdd(&gsum[t], a);
    atomicAdd(&gsum2[t], b);
  }
}

__global__ void k_bnfinal(const float* __restrict__ gsum, const float* __restrict__ gsum2,
                          const float* __restrict__ g, const float* __restrict__ bt,
                          float* __restrict__ ab, float Ninv) {
  int f = threadIdx.x;
  if (f < 64) {
    float mu = gsum[f] * Ninv;
    float var = gsum2[f] * Ninv - mu * mu;
    float a = g[f] / sqrtf(var + EPS_BN);
    ab[f] = a;
    ab[64 + f] = bt[f] - mu * a;
  }
}

__global__ void k_bnapply(const float* __restrict__ H, const float* __restrict__ ab,
                          float* __restrict__ A, int total) {
  int i = blockIdx.x * 256 + threadIdx.x;
  if (i < total) {
    int f = i & 63;
    A[i] = H[i] * ab[f] + ab[64 + f];
  }
}

// ---------------- row L2 normalize (F=32) ----------------
__global__ void k_norm(float* __restrict__ H, int N) {
  int idx = blockIdx.x * 256 + threadIdx.x;
  int n = idx >> 5, f = idx & 31;
  if (n >= N) return;
  float v = H[n * 32 + f];
  float s = v * v;
  for (int off = 16; off; off >>= 1) s += __shfl_xor(s, off, 32);
  float nrm = sqrtf(s);
  nrm = fmaxf(nrm, 1e-12f);
  H[n * 32 + f] = v / nrm;
}

// ---------------- pooling ----------------
__device__ __forceinline__ unsigned fkey(float x) {
  unsigned u = __float_as_uint(x);
  return (u & 0x80000000u) ? ~u : (u | 0x80000000u);
}
__device__ __forceinline__ float fdec(unsigned u) {
  return (u & 0x80000000u) ? __uint_as_float(u & 0x7FFFFFFFu) : __uint_as_float(~u);
}

// segmented pooling over sorted batch: per-thread register accumulation,
// atomics only at graph boundaries (~200k total vs 9.6M naive)
#define POOL_CHUNK 512
__global__ void k_pool2(const float* __restrict__ H, const int* __restrict__ batch,
                        float* __restrict__ psum, unsigned* __restrict__ pmax,
                        unsigned* __restrict__ pmin, float* __restrict__ pcnt, int N) {
  int f = threadIdx.x & 31;
  int sub = threadIdx.x >> 5;  // 0..7
  int n0 = blockIdx.x * POOL_CHUNK;
  int n1 = n0 + POOL_CHUNK; if (n1 > N) n1 = N;
  int curg = -1;
  float s = 0.f, mx = -3.4e38f, mn = 3.4e38f, cnt = 0.f;
  for (int n = n0 + sub; n < n1; n += 8) {
    int g = batch[n];
    if (g != curg) {
      if (curg >= 0) {
        atomicAdd(&psum[curg * 32 + f], s);
        atomicMax(&pmax[curg * 32 + f], fkey(mx));
        atomicMin(&pmin[curg * 32 + f], fkey(mn));
        if (f == 0) atomicAdd(&pcnt[curg], cnt);
      }
      curg = g; s = 0.f; mx = -3.4e38f; mn = 3.4e38f; cnt = 0.f;
    }
    float v = H[n * 32 + f];
    s += v; mx = fmaxf(mx, v); mn = fminf(mn, v); cnt += 1.f;
  }
  if (curg >= 0) {
    atomicAdd(&psum[curg * 32 + f], s);
    atomicMax(&pmax[curg * 32 + f], fkey(mx));
    atomicMin(&pmin[curg * 32 + f], fkey(mn));
    if (f == 0) atomicAdd(&pcnt[curg], cnt);
  }
}

__global__ void k_poolfin(const float* __restrict__ psum, const unsigned* __restrict__ pmax,
                          const unsigned* __restrict__ pmin, const float* __restrict__ pcnt,
                          float* __restrict__ out) {
  int g = blockIdx.x, f = threadIdx.x;  // 64 x 32
  float s = psum[g * 32 + f];
  float c = fmaxf(pcnt[g], 1.0f);
  out[g * 128 + f] = s / c;
  out[g * 128 + 32 + f] = fdec(pmax[g * 32 + f]);
  out[g * 128 + 64 + f] = fdec(pmin[g * 32 + f]);
  out[g * 128 + 96 + f] = s;
}

// ---------------- host ----------------

extern "C" void kernel_launch(void* const* d_in, const int* in_sizes, int n_in,
                              void* d_out, int out_size, void* d_ws, size_t ws_size,
                              hipStream_t stream) {
  const float* x   = (const float*)d_in[0];
  const int*   ei  = (const int*)d_in[1];
  const int*   bat = (const int*)d_in[2];
  const float* W1  = (const float*)d_in[3];  const float* bc1 = (const float*)d_in[4];
  const float* W2  = (const float*)d_in[5];  const float* bc2 = (const float*)d_in[6];
  const float* W3  = (const float*)d_in[7];  const float* bc3 = (const float*)d_in[8];
  const float* W4  = (const float*)d_in[9];  const float* bc4 = (const float*)d_in[10];
  const float* g1  = (const float*)d_in[11]; const float* bt1 = (const float*)d_in[12];
  const float* g2  = (const float*)d_in[13]; const float* bt2 = (const float*)d_in[14];
  const float* g3  = (const float*)d_in[15]; const float* bt3 = (const float*)d_in[16];

  const int N = in_sizes[0] / 3;
  const int E = in_sizes[1] / 2;
  const int* src = ei;
  const int* dst = ei + E;

  // ---- workspace layout (float-element granularity, 64-elt aligned) ----
  float* base = (float*)d_ws;
  size_t o = 0;
  auto alloc = [&](size_t n) -> float* {
    float* p = base + o;
    o += (n + 63) & ~(size_t)63;
    return p;
  };
  // zeroed region (contiguous from d_ws start):
  float* deg    = alloc(N);           // becomes dinv in-place
  int*   hist   = (int*)alloc(N);
  int*   cursor = (int*)alloc(N);
  float* bnacc  = alloc(6 * 64);      // [layer][sum|sum2][64] -> 3 pairs
  float* psum   = alloc(64 * 32);
  float* pcnt   = alloc(64);
  unsigned* pmax = (unsigned*)alloc(64 * 32);
  size_t zero_elems = o;
  // 0xFF region:
  unsigned* pmin = (unsigned*)alloc(64 * 32);
  // uninitialized (fully overwritten before read):
  int*   offs = (int*)alloc(N + 1);
  int*   ssrc = (int*)alloc(E);
  float* sew  = alloc(E);
  float* ab   = alloc(128);
  float* A    = alloc((size_t)N * 64);
  float* B    = alloc((size_t)N * 64);
  float* H    = alloc((size_t)N * 64);

  hipMemsetAsync(d_ws, 0, zero_elems * sizeof(float), stream);
  hipMemsetAsync(pmin, 0xFF, 64 * 32 * sizeof(unsigned), stream);

  const int EB = (E + 255) / 256;
  const int NB = (N + 255) / 256;

  // ---- build dinv + CSR(dst) ----
  k_deg<<<EB, 256, 0, stream>>>(src, deg, E);
  k_dinv<<<NB, 256, 0, stream>>>(deg, N);
  k_hist<<<EB, 256, 0, stream>>>(dst, hist, E);
  k_scan<<<1, 1024, 0, stream>>>(hist, offs, N, E);
  k_scatter<<<EB, 256, 0, stream>>>(src, dst, deg, offs, cursor, ssrc, sew, E);

  const int PB64 = (N * 64 + 255) / 256;  // wave-per-node blocks
  const int CB64 = (N + 3) / 4;
  const int CB32 = (N + 7) / 8;

  auto comb64 = [&](const float* TxA, const float* WA, const float* TxB, const float* WB,
                    const float* bias, int Fin, int mode) {
    size_t sh = (size_t)(TxB ? 2 : 1) * Fin * 64 * sizeof(float);
    k_combine<64><<<CB64, 256, sh, stream>>>(H, TxA, WA, TxB, WB, bias, N, Fin, mode);
  };
  auto comb32 = [&](const float* TxA, const float* WA, const float* TxB, const float* WB,
                    const float* bias, int Fin, int mode) {
    size_t sh = (size_t)(TxB ? 2 : 1) * Fin * 32 * sizeof(float);
    k_combine<32><<<CB32, 256, sh, stream>>>(H, TxA, WA, TxB, WB, bias, N, Fin, mode);
  };

  // ---- layer 1: Fin=3 -> 64 ----
  {
    const float* W = W1;
    k_prop3<<<NB, 256, 0, stream>>>(x, nullptr, B, offs, ssrc, sew, N, 0);        // B = L x
    comb64(x, W + 0 * 192, B, W + 1 * 192, bc1, 3, 0);                            // H = b + xW0 + BW1
    k_prop3<<<NB, 256, 0, stream>>>(B, x, A, offs, ssrc, sew, N, 1);              // A = 2LB - x
    comb64(A, W + 2 * 192, nullptr, nullptr, nullptr, 3, 1);                      // H += AW2
    k_prop3<<<NB, 256, 0, stream>>>(A, B, B, offs, ssrc, sew, N, 1);              // B = 2LA - B
    comb64(B, W + 3 * 192, nullptr, nullptr, nullptr, 3, 1);                      // H += BW3
    k_bnstats<<<256, 256, 0, stream>>>(H, bnacc + 0, bnacc + 64, N);
    k_bnfinal<<<1, 64, 0, stream>>>(bnacc + 0, bnacc + 64, g1, bt1, ab, 1.0f / N);
    k_bnapply<<<PB64, 256, 0, stream>>>(H, ab, A, N * 64);                        // A = Tx0 of layer2
  }

  // ---- layers 2 & 3: 64 -> 64 ----
  const float* Ws[2] = {W2, W3};
  const float* bs[2] = {bc2, bc3};
  const float* gs[2] = {g2, g3};
  const float* bts[2] = {bt2, bt3};
  for (int L = 0; L < 2; L++) {
    const float* W = Ws[L];
    k_prop64<<<PB64, 256, 0, stream>>>(A, nullptr, B, offs, ssrc, sew, N, 0);     // B = LA
    comb64(A, W + 0 * 4096, B, W + 1 * 4096, bs[L], 64, 0);
    k_prop64<<<PB64, 256, 0, stream>>>(B, A, A, offs, ssrc, sew, N, 1);           // A = 2LB - A
    comb64(A, W + 2 * 4096, nullptr, nullptr, nullptr, 64, 1);
    k_prop64<<<PB64, 256, 0, stream>>>(A, B, B, offs, ssrc, sew, N, 1);           // B = 2LA - B
    comb64(B, W + 3 * 4096, nullptr, nullptr, nullptr, 64, 1);
    k_bnstats<<<256, 256, 0, stream>>>(H, bnacc + (L + 1) * 128, bnacc + (L + 1) * 128 + 64, N);
    k_bnfinal<<<1, 64, 0, stream>>>(bnacc + (L + 1) * 128, bnacc + (L + 1) * 128 + 64,
                                    gs[L], bts[L], ab, 1.0f / N);
    k_bnapply<<<PB64, 256, 0, stream>>>(H, ab, A, N * 64);
  }

  // ---- layer 4: 64 -> 32 ----
  {
    const float* W = W4;
    k_prop64<<<PB64, 256, 0, stream>>>(A, nullptr, B, offs, ssrc, sew, N, 0);
    comb32(A, W + 0 * 2048, B, W + 1 * 2048, bc4, 64, 0);
    k_prop64<<<PB64, 256, 0, stream>>>(B, A, A, offs, ssrc, sew, N, 1);
    comb32(A, W + 2 * 2048, nullptr, nullptr, nullptr, 64, 1);
    k_prop64<<<PB64, 256, 0, stream>>>(A, B, B, offs, ssrc, sew, N, 1);
    comb32(B, W + 3 * 2048, nullptr, nullptr, nullptr, 64, 1);
  }

  // ---- normalize + pool ----
  const int RB32 = (N * 32 + 255) / 256;
  k_norm<<<RB32, 256, 0, stream>>>(H, N);
  k_pool2<<<(N + POOL_CHUNK - 1) / POOL_CHUNK, 256, 0, stream>>>(H, bat, psum, pmax, pmin, pcnt, N);
  k_poolfin<<<64, 32, 0, stream>>>(psum, pmax, pmin, pcnt, (float*)d_out);
}

// Round 3
// 2110.925 us; speedup vs baseline: 1.7239x; 1.3184x over previous
//
#include <hip/hip_runtime.h>

#define EPS_BN 1e-5f

// ---------------- preprocessing ----------------

__global__ void k_deg(const int* __restrict__ src, float* __restrict__ deg, int E) {
  int e = blockIdx.x * 256 + threadIdx.x;
  if (e < E) atomicAdd(&deg[src[e]], 1.0f);
}

__global__ void k_dinv(float* __restrict__ deg, int N) {
  int i = blockIdx.x * 256 + threadIdx.x;
  if (i < N) { float d = deg[i]; deg[i] = d > 0.f ? 1.0f / sqrtf(d) : 0.f; }
}

__global__ void k_hist(const int* __restrict__ dst, int* __restrict__ hist, int E) {
  int e = blockIdx.x * 256 + threadIdx.x;
  if (e < E) atomicAdd(&hist[dst[e]], 1);
}

// ---- hierarchical scan: 250 blocks x 400 bins ----
#define SC_CHUNK 400

__device__ __forceinline__ int lds_incl_scan256(int* lds, int t, int v) {
  lds[t] = v; __syncthreads();
  for (int off = 1; off < 256; off <<= 1) {
    int u = (t >= off) ? lds[t - off] : 0;
    __syncthreads();
    lds[t] += u;
    __syncthreads();
  }
  return lds[t];
}

__global__ void k_scan1(const int* __restrict__ hist, int* __restrict__ bsum, int N) {
  __shared__ int lds[256];
  int b = blockIdx.x, t = threadIdx.x;
  int lo = b * SC_CHUNK;
  int hi = lo + SC_CHUNK; if (hi > N) hi = N;
  int i0 = lo + t * 2;
  int s = 0;
  if (i0 < hi) s += hist[i0];
  if (i0 + 1 < hi) s += hist[i0 + 1];
  int incl = lds_incl_scan256(lds, t, s);
  if (t == 255) bsum[b] = incl;
}

__global__ void k_scan2(const int* __restrict__ bsum, int* __restrict__ bbase, int nb) {
  __shared__ int lds[256];
  int t = threadIdx.x;
  int v = (t < nb) ? bsum[t] : 0;
  int incl = lds_incl_scan256(lds, t, v);
  if (t < nb) bbase[t] = incl - v;  // exclusive
}

__global__ void k_scan3(const int* __restrict__ hist, const int* __restrict__ bbase,
                        int* __restrict__ offs, int N, int E) {
  __shared__ int lds[256];
  int b = blockIdx.x, t = threadIdx.x;
  int lo = b * SC_CHUNK;
  int hi = lo + SC_CHUNK; if (hi > N) hi = N;
  int i0 = lo + t * 2;
  int h0 = (i0 < hi) ? hist[i0] : 0;
  int h1 = (i0 + 1 < hi) ? hist[i0 + 1] : 0;
  int s = h0 + h1;
  int incl = lds_incl_scan256(lds, t, s);
  int run = bbase[b] + incl - s;
  if (i0 < hi) offs[i0] = run;
  if (i0 + 1 < hi) offs[i0 + 1] = run + h0;
  if (b == 0 && t == 0) offs[N] = E;
}

__global__ void k_scatter(const int* __restrict__ src, const int* __restrict__ dst,
                          const float* __restrict__ dinv, const int* __restrict__ offs,
                          int* __restrict__ cursor, int* __restrict__ ssrc,
                          float* __restrict__ sew, int E) {
  int e = blockIdx.x * 256 + threadIdx.x;
  if (e >= E) return;
  int s = src[e], d = dst[e];
  int pos = offs[d] + atomicAdd(&cursor[d], 1);
  ssrc[pos] = s;
  sew[pos] = -dinv[s] * dinv[d];
}

// ---------------- propagation (CSR by dst, no atomics) ----------------
__global__ void k_prop64(const float* __restrict__ gf, const float* __restrict__ oldv,
                         float* __restrict__ outv, const int* __restrict__ offs,
                         const int* __restrict__ ssrc, const float* __restrict__ sew,
                         int N, int recur) {
  int wid = (blockIdx.x * 256 + threadIdx.x) >> 6;
  int lane = threadIdx.x & 63;
  if (wid >= N) return;
  int r0 = offs[wid], r1 = offs[wid + 1];
  float acc = 0.f;
  for (int e = r0; e < r1; e++) {
    int s = ssrc[e];
    float w = sew[e];
    acc += w * gf[s * 64 + lane];
  }
  int idx = wid * 64 + lane;
  if (recur) outv[idx] = 2.f * acc - oldv[idx];
  else       outv[idx] = acc;
}

__global__ void k_prop3(const float* __restrict__ gf, const float* __restrict__ oldv,
                        float* __restrict__ outv, const int* __restrict__ offs,
                        const int* __restrict__ ssrc, const float* __restrict__ sew,
                        int N, int recur) {
  int n = blockIdx.x * 256 + threadIdx.x;
  if (n >= N) return;
  int r0 = offs[n], r1 = offs[n + 1];
  float a0 = 0.f, a1 = 0.f, a2 = 0.f;
  for (int e = r0; e < r1; e++) {
    int s = ssrc[e];
    float w = sew[e];
    a0 += w * gf[s * 3 + 0];
    a1 += w * gf[s * 3 + 1];
    a2 += w * gf[s * 3 + 2];
  }
  if (recur) {
    a0 = 2.f * a0 - oldv[n * 3 + 0];
    a1 = 2.f * a1 - oldv[n * 3 + 1];
    a2 = 2.f * a2 - oldv[n * 3 + 2];
  }
  outv[n * 3 + 0] = a0;
  outv[n * 3 + 1] = a1;
  outv[n * 3 + 2] = a2;
}

// ---------------- tiled combine (Fin=64): H = [bias|H] + TxA@WA (+TxB@WB) ----------------
// block = FOUT*4 threads, tile = 64 nodes; thread computes 4 nodes x 4 outs.
template <int FOUT>
__global__ void k_combine_t(float* __restrict__ H, const float* __restrict__ TxA,
                            const float* __restrict__ WA, const float* __restrict__ TxB,
                            const float* __restrict__ WB, const float* __restrict__ bias,
                            int N, int mode) {
  constexpr int PADT = 68;
  constexpr int PADW = FOUT + 4;
  __shared__ float TxT[64 * PADT];  // [i][n] transposed
  __shared__ float WS[64 * PADW];   // [i][j]
  int tid = threadIdx.x;
  int n_base = blockIdx.x * 64;
  int tj = tid % (FOUT / 4);
  int tn = tid / (FOUT / 4);  // 0..15
  int j0 = tj * 4, n0 = tn * 4;

  float acc[4][4];
  if (mode == 0) {
    float4 b = *(const float4*)(bias + j0);
    for (int a = 0; a < 4; a++) { acc[a][0] = b.x; acc[a][1] = b.y; acc[a][2] = b.z; acc[a][3] = b.w; }
  } else {
    for (int a = 0; a < 4; a++) {
      int n = n_base + n0 + a;
      if (n < N) {
        float4 h = *(const float4*)(H + (size_t)n * FOUT + j0);
        acc[a][0] = h.x; acc[a][1] = h.y; acc[a][2] = h.z; acc[a][3] = h.w;
      } else {
        acc[a][0] = acc[a][1] = acc[a][2] = acc[a][3] = 0.f;
      }
    }
  }

  int npass = TxB ? 2 : 1;
  for (int pass = 0; pass < npass; pass++) {
    const float* Tx = pass ? TxB : TxA;
    const float* W = pass ? WB : WA;
    if (pass) __syncthreads();
    // stage W [64 x FOUT]
    for (int idx = tid; idx < 64 * FOUT / 4; idx += blockDim.x) {
      int r = idx / (FOUT / 4), c4 = idx % (FOUT / 4);
      float4 w = *(const float4*)(W + r * FOUT + c4 * 4);
      float* p = &WS[r * PADW + c4 * 4];
      p[0] = w.x; p[1] = w.y; p[2] = w.z; p[3] = w.w;
    }
    // stage Tx transposed [64 nodes x 64 feats]
    for (int idx = tid; idx < 64 * 16; idx += blockDim.x) {
      int r = idx / 16, c4 = idx % 16;
      int n = n_base + r;
      float4 t = (n < N) ? *(const float4*)(Tx + (size_t)n * 64 + c4 * 4)
                         : make_float4(0.f, 0.f, 0.f, 0.f);
      TxT[(c4 * 4 + 0) * PADT + r] = t.x;
      TxT[(c4 * 4 + 1) * PADT + r] = t.y;
      TxT[(c4 * 4 + 2) * PADT + r] = t.z;
      TxT[(c4 * 4 + 3) * PADT + r] = t.w;
    }
    __syncthreads();
#pragma unroll 8
    for (int i = 0; i < 64; i++) {
      float4 tx = *(const float4*)(&TxT[i * PADT + n0]);
      float4 w = *(const float4*)(&WS[i * PADW + j0]);
      acc[0][0] += tx.x * w.x; acc[0][1] += tx.x * w.y; acc[0][2] += tx.x * w.z; acc[0][3] += tx.x * w.w;
      acc[1][0] += tx.y * w.x; acc[1][1] += tx.y * w.y; acc[1][2] += tx.y * w.z; acc[1][3] += tx.y * w.w;
      acc[2][0] += tx.z * w.x; acc[2][1] += tx.z * w.y; acc[2][2] += tx.z * w.z; acc[2][3] += tx.z * w.w;
      acc[3][0] += tx.w * w.x; acc[3][1] += tx.w * w.y; acc[3][2] += tx.w * w.z; acc[3][3] += tx.w * w.w;
    }
  }

  for (int a = 0; a < 4; a++) {
    int n = n_base + n0 + a;
    if (n < N)
      *(float4*)(H + (size_t)n * FOUT + j0) = make_float4(acc[a][0], acc[a][1], acc[a][2], acc[a][3]);
  }
}

// ---------------- simple combine for Fin=3 (layer 1) ----------------
__global__ void k_combine3(float* __restrict__ H, const float* __restrict__ TxA,
                           const float* __restrict__ WA, const float* __restrict__ TxB,
                           const float* __restrict__ WB, const float* __restrict__ bias,
                           int N, int mode) {
  __shared__ float wa[3 * 64], wb[3 * 64];
  int tid = threadIdx.x;
  if (tid < 192) wa[tid] = WA[tid];
  if (TxB && tid < 192) wb[tid] = WB[tid];
  __syncthreads();
  int n = blockIdx.x * 4 + tid / 64;
  int j = tid % 64;
  if (n >= N) return;
  float acc = mode ? H[n * 64 + j] : bias[j];
  for (int i = 0; i < 3; i++) acc += TxA[n * 3 + i] * wa[i * 64 + j];
  if (TxB) for (int i = 0; i < 3; i++) acc += TxB[n * 3 + i] * wb[i * 64 + j];
  H[n * 64 + j] = acc;
}

// ---------------- LeakyReLU + BN stats (float4, per-block partials) ----------------
#define BN_GRID 400
__global__ void k_bnstats(float* __restrict__ H, float* __restrict__ gpart, int N) {
  __shared__ float red[256 * 8];
  int t = threadIdx.x;
  int f4 = t & 15, r = t >> 4;  // 16 f4-groups x 16 rows
  float4* H4 = (float4*)H;
  float s0 = 0.f, s1 = 0.f, s2 = 0.f, s3 = 0.f;
  float q0 = 0.f, q1 = 0.f, q2 = 0.f, q3 = 0.f;
  for (int n = blockIdx.x * 16 + r; n < N; n += BN_GRID * 16) {
    float4 v = H4[(size_t)n * 16 + f4];
    v.x = v.x >= 0.f ? v.x : 0.01f * v.x;
    v.y = v.y >= 0.f ? v.y : 0.01f * v.y;
    v.z = v.z >= 0.f ? v.z : 0.01f * v.z;
    v.w = v.w >= 0.f ? v.w : 0.01f * v.w;
    H4[(size_t)n * 16 + f4] = v;
    s0 += v.x; s1 += v.y; s2 += v.z; s3 += v.w;
    q0 += v.x * v.x; q1 += v.y * v.y; q2 += v.z * v.z; q3 += v.w * v.w;
  }
  float* rp = &red[t * 8];
  rp[0] = s0; rp[1] = s1; rp[2] = s2; rp[3] = s3;
  rp[4] = q0; rp[5] = q1; rp[6] = q2; rp[7] = q3;
  __syncthreads();
  if (t < 64) {
    int f4g = t >> 2, k = t & 3;
    float a = 0.f, b = 0.f;
    for (int rr = 0; rr < 16; rr++) {
      a += red[(rr * 16 + f4g) * 8 + k];
      b += red[(rr * 16 + f4g) * 8 + 4 + k];
    }
    gpart[blockIdx.x * 128 + t] = a;
    gpart[blockIdx.x * 128 + 64 + t] = b;
  }
}

__global__ void k_bnfinal(const float* __restrict__ gpart, const float* __restrict__ g,
                          const float* __restrict__ bt, float* __restrict__ ab, float Ninv) {
  int t = threadIdx.x;  // 128
  float s = 0.f;
  for (int b = 0; b < BN_GRID; b++) s += gpart[b * 128 + t];
  __shared__ float red[128];
  red[t] = s; __syncthreads();
  if (t < 64) {
    float mu = red[t] * Ninv;
    float var = red[64 + t] * Ninv - mu * mu;
    float a = g[t] / sqrtf(var + EPS_BN);
    ab[t] = a;
    ab[64 + t] = bt[t] - mu * a;
  }
}

__global__ void k_bnapply(const float* __restrict__ H, const float* __restrict__ ab,
                          float* __restrict__ A, int n4) {
  int i = blockIdx.x * 256 + threadIdx.x;
  if (i >= n4) return;
  int f4 = i & 15;
  const float4* ab4 = (const float4*)ab;
  float4 sc = ab4[f4], sh = ab4[16 + f4];
  float4 v = ((const float4*)H)[i];
  v.x = v.x * sc.x + sh.x;
  v.y = v.y * sc.y + sh.y;
  v.z = v.z * sc.z + sh.z;
  v.w = v.w * sc.w + sh.w;
  ((float4*)A)[i] = v;
}

// ---------------- row L2 normalize (F=32) ----------------
__global__ void k_norm(float* __restrict__ H, int N) {
  int idx = blockIdx.x * 256 + threadIdx.x;
  int n = idx >> 5, f = idx & 31;
  if (n >= N) return;
  float v = H[n * 32 + f];
  float s = v * v;
  for (int off = 16; off; off >>= 1) s += __shfl_xor(s, off, 32);
  float nrm = sqrtf(s);
  nrm = fmaxf(nrm, 1e-12f);
  H[n * 32 + f] = v / nrm;
}

// ---------------- pooling ----------------
__device__ __forceinline__ unsigned fkey(float x) {
  unsigned u = __float_as_uint(x);
  return (u & 0x80000000u) ? ~u : (u | 0x80000000u);
}
__device__ __forceinline__ float fdec(unsigned u) {
  return (u & 0x80000000u) ? __uint_as_float(u & 0x7FFFFFFFu) : __uint_as_float(~u);
}

#define POOL_CHUNK 512
__global__ void k_pool2(const float* __restrict__ H, const int* __restrict__ batch,
                        float* __restrict__ psum, unsigned* __restrict__ pmax,
                        unsigned* __restrict__ pmin, float* __restrict__ pcnt, int N) {
  int f = threadIdx.x & 31;
  int sub = threadIdx.x >> 5;
  int n0 = blockIdx.x * POOL_CHUNK;
  int n1 = n0 + POOL_CHUNK; if (n1 > N) n1 = N;
  int curg = -1;
  float s = 0.f, mx = -3.4e38f, mn = 3.4e38f, cnt = 0.f;
  for (int n = n0 + sub; n < n1; n += 8) {
    int g = batch[n];
    if (g != curg) {
      if (curg >= 0) {
        atomicAdd(&psum[curg * 32 + f], s);
        atomicMax(&pmax[curg * 32 + f], fkey(mx));
        atomicMin(&pmin[curg * 32 + f], fkey(mn));
        if (f == 0) atomicAdd(&pcnt[curg], cnt);
      }
      curg = g; s = 0.f; mx = -3.4e38f; mn = 3.4e38f; cnt = 0.f;
    }
    float v = H[n * 32 + f];
    s += v; mx = fmaxf(mx, v); mn = fminf(mn, v); cnt += 1.f;
  }
  if (curg >= 0) {
    atomicAdd(&psum[curg * 32 + f], s);
    atomicMax(&pmax[curg * 32 + f], fkey(mx));
    atomicMin(&pmin[curg * 32 + f], fkey(mn));
    if (f == 0) atomicAdd(&pcnt[curg], cnt);
  }
}

__global__ void k_poolfin(const float* __restrict__ psum, const unsigned* __restrict__ pmax,
                          const unsigned* __restrict__ pmin, const float* __restrict__ pcnt,
                          float* __restrict__ out) {
  int g = blockIdx.x, f = threadIdx.x;
  float s = psum[g * 32 + f];
  float c = fmaxf(pcnt[g], 1.0f);
  out[g * 128 + f] = s / c;
  out[g * 128 + 32 + f] = fdec(pmax[g * 32 + f]);
  out[g * 128 + 64 + f] = fdec(pmin[g * 32 + f]);
  out[g * 128 + 96 + f] = s;
}

// ---------------- host ----------------

extern "C" void kernel_launch(void* const* d_in, const int* in_sizes, int n_in,
                              void* d_out, int out_size, void* d_ws, size_t ws_size,
                              hipStream_t stream) {
  const float* x   = (const float*)d_in[0];
  const int*   ei  = (const int*)d_in[1];
  const int*   bat = (const int*)d_in[2];
  const float* W1  = (const float*)d_in[3];  const float* bc1 = (const float*)d_in[4];
  const float* W2  = (const float*)d_in[5];  const float* bc2 = (const float*)d_in[6];
  const float* W3  = (const float*)d_in[7];  const float* bc3 = (const float*)d_in[8];
  const float* W4  = (const float*)d_in[9];  const float* bc4 = (const float*)d_in[10];
  const float* g1  = (const float*)d_in[11]; const float* bt1 = (const float*)d_in[12];
  const float* g2  = (const float*)d_in[13]; const float* bt2 = (const float*)d_in[14];
  const float* g3  = (const float*)d_in[15]; const float* bt3 = (const float*)d_in[16];

  const int N = in_sizes[0] / 3;
  const int E = in_sizes[1] / 2;
  const int* src = ei;
  const int* dst = ei + E;

  float* base = (float*)d_ws;
  size_t o = 0;
  auto alloc = [&](size_t n) -> float* {
    float* p = base + o;
    o += (n + 63) & ~(size_t)63;
    return p;
  };
  // zeroed region:
  float* deg    = alloc(N);
  int*   hist   = (int*)alloc(N);
  int*   cursor = (int*)alloc(N);
  float* psum   = alloc(64 * 32);
  float* pcnt   = alloc(64);
  unsigned* pmax = (unsigned*)alloc(64 * 32);
  size_t zero_elems = o;
  // 0xFF region:
  unsigned* pmin = (unsigned*)alloc(64 * 32);
  // uninitialized:
  int*   offs  = (int*)alloc(N + 1);
  int*   bsum  = (int*)alloc(256);
  int*   bbase = (int*)alloc(256);
  float* gpart = alloc(BN_GRID * 128);
  int*   ssrc  = (int*)alloc(E);
  float* sew   = alloc(E);
  float* ab    = alloc(128);
  float* A     = alloc((size_t)N * 64);
  float* B     = alloc((size_t)N * 64);
  float* H     = alloc((size_t)N * 64);

  hipMemsetAsync(d_ws, 0, zero_elems * sizeof(float), stream);
  hipMemsetAsync(pmin, 0xFF, 64 * 32 * sizeof(unsigned), stream);

  const int EB = (E + 255) / 256;
  const int NB = (N + 255) / 256;
  const int SB = (N + SC_CHUNK - 1) / SC_CHUNK;

  k_deg<<<EB, 256, 0, stream>>>(src, deg, E);
  k_dinv<<<NB, 256, 0, stream>>>(deg, N);
  k_hist<<<EB, 256, 0, stream>>>(dst, hist, E);
  k_scan1<<<SB, 256, 0, stream>>>(hist, bsum, N);
  k_scan2<<<1, 256, 0, stream>>>(bsum, bbase, SB);
  k_scan3<<<SB, 256, 0, stream>>>(hist, bbase, offs, N, E);
  k_scatter<<<EB, 256, 0, stream>>>(src, dst, deg, offs, cursor, ssrc, sew, E);

  const int PB64 = (N * 64 + 255) / 256;
  const int TB = (N + 63) / 64;  // tiled combine blocks

  auto comb64 = [&](const float* TxA, const float* WA, const float* TxB, const float* WB,
                    const float* bias, int mode) {
    k_combine_t<64><<<TB, 256, 0, stream>>>(H, TxA, WA, TxB, WB, bias, N, mode);
  };
  auto comb32 = [&](const float* TxA, const float* WA, const float* TxB, const float* WB,
                    const float* bias, int mode) {
    k_combine_t<32><<<TB, 128, 0, stream>>>(H, TxA, WA, TxB, WB, bias, N, mode);
  };

  // ---- layer 1: Fin=3 -> 64 ----
  {
    const float* W = W1;
    k_prop3<<<NB, 256, 0, stream>>>(x, nullptr, B, offs, ssrc, sew, N, 0);
    k_combine3<<<(N + 3) / 4, 256, 0, stream>>>(H, x, W + 0 * 192, B, W + 1 * 192, bc1, N, 0);
    k_prop3<<<NB, 256, 0, stream>>>(B, x, A, offs, ssrc, sew, N, 1);
    k_combine3<<<(N + 3) / 4, 256, 0, stream>>>(H, A, W + 2 * 192, nullptr, nullptr, nullptr, N, 1);
    k_prop3<<<NB, 256, 0, stream>>>(A, B, B, offs, ssrc, sew, N, 1);
    k_combine3<<<(N + 3) / 4, 256, 0, stream>>>(H, B, W + 3 * 192, nullptr, nullptr, nullptr, N, 1);
    k_bnstats<<<BN_GRID, 256, 0, stream>>>(H, gpart, N);
    k_bnfinal<<<1, 128, 0, stream>>>(gpart, g1, bt1, ab, 1.0f / N);
    k_bnapply<<<(N * 16 + 255) / 256, 256, 0, stream>>>(H, ab, A, N * 16);
  }

  // ---- layers 2 & 3: 64 -> 64 ----
  const float* Ws[2] = {W2, W3};
  const float* bs[2] = {bc2, bc3};
  const float* gs[2] = {g2, g3};
  const float* bts[2] = {bt2, bt3};
  for (int L = 0; L < 2; L++) {
    const float* W = Ws[L];
    k_prop64<<<PB64, 256, 0, stream>>>(A, nullptr, B, offs, ssrc, sew, N, 0);
    comb64(A, W + 0 * 4096, B, W + 1 * 4096, bs[L], 0);
    k_prop64<<<PB64, 256, 0, stream>>>(B, A, A, offs, ssrc, sew, N, 1);
    comb64(A, W + 2 * 4096, nullptr, nullptr, nullptr, 1);
    k_prop64<<<PB64, 256, 0, stream>>>(A, B, B, offs, ssrc, sew, N, 1);
    comb64(B, W + 3 * 4096, nullptr, nullptr, nullptr, 1);
    k_bnstats<<<BN_GRID, 256, 0, stream>>>(H, gpart, N);
    k_bnfinal<<<1, 128, 0, stream>>>(gpart, gs[L], bts[L], ab, 1.0f / N);
    k_bnapply<<<(N * 16 + 255) / 256, 256, 0, stream>>>(H, ab, A, N * 16);
  }

  // ---- layer 4: 64 -> 32 ----
  {
    const float* W = W4;
    k_prop64<<<PB64, 256, 0, stream>>>(A, nullptr, B, offs, ssrc, sew, N, 0);
    comb32(A, W + 0 * 2048, B, W + 1 * 2048, bc4, 0);
    k_prop64<<<PB64, 256, 0, stream>>>(B, A, A, offs, ssrc, sew, N, 1);
    comb32(A, W + 2 * 2048, nullptr, nullptr, nullptr, 1);
    k_prop64<<<PB64, 256, 0, stream>>>(A, B, B, offs, ssrc, sew, N, 1);
    comb32(B, W + 3 * 2048, nullptr, nullptr, nullptr, 1);
  }

  // ---- normalize + pool ----
  const int RB32 = (N * 32 + 255) / 256;
  k_norm<<<RB32, 256, 0, stream>>>(H, N);
  k_pool2<<<(N + POOL_CHUNK - 1) / POOL_CHUNK, 256, 0, stream>>>(H, bat, psum, pmax, pmin, pcnt, N);
  k_poolfin<<<64, 32, 0, stream>>>(psum, pmax, pmin, pcnt, (float*)d_out);
}

// Round 4
// 1340.574 us; speedup vs baseline: 2.7145x; 1.5746x over previous
//
#include <hip/hip_runtime.h>

#define EPS_BN 1e-5f
#define ROWPAD 8  // CSR rows padded to multiple of 8 edges (src=0,w=0 filler)

// ---------------- preprocessing ----------------

__global__ void k_deg(const int* __restrict__ src, float* __restrict__ deg, int E) {
  int e = blockIdx.x * 256 + threadIdx.x;
  if (e < E) atomicAdd(&deg[src[e]], 1.0f);
}

__global__ void k_dinv(float* __restrict__ deg, int N) {
  int i = blockIdx.x * 256 + threadIdx.x;
  if (i < N) { float d = deg[i]; deg[i] = d > 0.f ? 1.0f / sqrtf(d) : 0.f; }
}

__global__ void k_hist(const int* __restrict__ dst, int* __restrict__ hist, int E) {
  int e = blockIdx.x * 256 + threadIdx.x;
  if (e < E) atomicAdd(&hist[dst[e]], 1);
}

// ---- hierarchical scan over PADDED counts: 250 blocks x 400 bins ----
#define SC_CHUNK 400

__device__ __forceinline__ int lds_incl_scan256(int* lds, int t, int v) {
  lds[t] = v; __syncthreads();
  for (int off = 1; off < 256; off <<= 1) {
    int u = (t >= off) ? lds[t - off] : 0;
    __syncthreads();
    lds[t] += u;
    __syncthreads();
  }
  return lds[t];
}

__device__ __forceinline__ int padcnt(int h) { return (h + (ROWPAD - 1)) & ~(ROWPAD - 1); }

__global__ void k_scan1(const int* __restrict__ hist, int* __restrict__ bsum, int N) {
  __shared__ int lds[256];
  int b = blockIdx.x, t = threadIdx.x;
  int lo = b * SC_CHUNK;
  int hi = lo + SC_CHUNK; if (hi > N) hi = N;
  int i0 = lo + t * 2;
  int s = 0;
  if (i0 < hi) s += padcnt(hist[i0]);
  if (i0 + 1 < hi) s += padcnt(hist[i0 + 1]);
  int incl = lds_incl_scan256(lds, t, s);
  if (t == 255) bsum[b] = incl;
}

__global__ void k_scan2(const int* __restrict__ bsum, int* __restrict__ bbase, int nb) {
  __shared__ int lds[256];
  int t = threadIdx.x;
  int v = (t < nb) ? bsum[t] : 0;
  int incl = lds_incl_scan256(lds, t, v);
  if (t < nb) bbase[t] = incl - v;  // exclusive
  if (t == nb - 1) bbase[nb] = incl;  // total padded edges
}

__global__ void k_scan3(const int* __restrict__ hist, const int* __restrict__ bbase,
                        int* __restrict__ offs, int N, int nb) {
  __shared__ int lds[256];
  int b = blockIdx.x, t = threadIdx.x;
  int lo = b * SC_CHUNK;
  int hi = lo + SC_CHUNK; if (hi > N) hi = N;
  int i0 = lo + t * 2;
  int h0 = (i0 < hi) ? padcnt(hist[i0]) : 0;
  int h1 = (i0 + 1 < hi) ? padcnt(hist[i0 + 1]) : 0;
  int s = h0 + h1;
  int incl = lds_incl_scan256(lds, t, s);
  int run = bbase[b] + incl - s;
  if (i0 < hi) offs[i0] = run;
  if (i0 + 1 < hi) offs[i0 + 1] = run + h0;
  if (b == 0 && t == 0) offs[N] = bbase[nb];
}

__global__ void k_scatter(const int* __restrict__ src, const int* __restrict__ dst,
                          const float* __restrict__ dinv, const int* __restrict__ offs,
                          int* __restrict__ cursor, int* __restrict__ ssrc,
                          float* __restrict__ sew, int E) {
  int e = blockIdx.x * 256 + threadIdx.x;
  if (e >= E) return;
  int s = src[e], d = dst[e];
  int pos = offs[d] + atomicAdd(&cursor[d], 1);
  ssrc[pos] = s;
  sew[pos] = -dinv[s] * dinv[d];
}

// ---------------- propagation (padded CSR, 8-wide MLP, no atomics) ----------------
__global__ void k_prop64(const float* __restrict__ gf, const float* __restrict__ oldv,
                         float* __restrict__ outv, const int* __restrict__ offs,
                         const int* __restrict__ ssrc, const float* __restrict__ sew,
                         int N, int recur) {
  int wid = (blockIdx.x * 256 + threadIdx.x) >> 6;
  int lane = threadIdx.x & 63;
  if (wid >= N) return;
  int r0 = offs[wid], r1 = offs[wid + 1];
  float acc = 0.f;
  for (int e = r0; e < r1; e += 8) {
    int4 sa = *(const int4*)(ssrc + e);
    int4 sb = *(const int4*)(ssrc + e + 4);
    float4 wa = *(const float4*)(sew + e);
    float4 wb = *(const float4*)(sew + e + 4);
    float g0 = gf[(size_t)sa.x * 64 + lane];
    float g1 = gf[(size_t)sa.y * 64 + lane];
    float g2 = gf[(size_t)sa.z * 64 + lane];
    float g3 = gf[(size_t)sa.w * 64 + lane];
    float g4 = gf[(size_t)sb.x * 64 + lane];
    float g5 = gf[(size_t)sb.y * 64 + lane];
    float g6 = gf[(size_t)sb.z * 64 + lane];
    float g7 = gf[(size_t)sb.w * 64 + lane];
    acc += wa.x * g0 + wa.y * g1 + wa.z * g2 + wa.w * g3
         + wb.x * g4 + wb.y * g5 + wb.z * g6 + wb.w * g7;
  }
  int idx = wid * 64 + lane;
  if (recur) outv[idx] = 2.f * acc - oldv[idx];
  else       outv[idx] = acc;
}

__global__ void k_prop3(const float* __restrict__ gf, const float* __restrict__ oldv,
                        float* __restrict__ outv, const int* __restrict__ offs,
                        const int* __restrict__ ssrc, const float* __restrict__ sew,
                        int N, int recur) {
  int n = blockIdx.x * 256 + threadIdx.x;
  if (n >= N) return;
  int r0 = offs[n], r1 = offs[n + 1];
  float a0 = 0.f, a1 = 0.f, a2 = 0.f;
  for (int e = r0; e < r1; e += 4) {
    int4 s4 = *(const int4*)(ssrc + e);
    float4 w4 = *(const float4*)(sew + e);
    a0 += w4.x * gf[s4.x * 3 + 0]; a1 += w4.x * gf[s4.x * 3 + 1]; a2 += w4.x * gf[s4.x * 3 + 2];
    a0 += w4.y * gf[s4.y * 3 + 0]; a1 += w4.y * gf[s4.y * 3 + 1]; a2 += w4.y * gf[s4.y * 3 + 2];
    a0 += w4.z * gf[s4.z * 3 + 0]; a1 += w4.z * gf[s4.z * 3 + 1]; a2 += w4.z * gf[s4.z * 3 + 2];
    a0 += w4.w * gf[s4.w * 3 + 0]; a1 += w4.w * gf[s4.w * 3 + 1]; a2 += w4.w * gf[s4.w * 3 + 2];
  }
  if (recur) {
    a0 = 2.f * a0 - oldv[n * 3 + 0];
    a1 = 2.f * a1 - oldv[n * 3 + 1];
    a2 = 2.f * a2 - oldv[n * 3 + 2];
  }
  outv[n * 3 + 0] = a0;
  outv[n * 3 + 1] = a1;
  outv[n * 3 + 2] = a2;
}

// ---------------- tiled combine (Fin=64): H = [bias|H] + TxA@WA (+TxB@WB) ----------------
template <int FOUT>
__global__ void k_combine_t(float* __restrict__ H, const float* __restrict__ TxA,
                            const float* __restrict__ WA, const float* __restrict__ TxB,
                            const float* __restrict__ WB, const float* __restrict__ bias,
                            int N, int mode) {
  constexpr int PADT = 68;
  constexpr int PADW = FOUT + 4;
  __shared__ float TxT[64 * PADT];  // [i][n] transposed
  __shared__ float WS[64 * PADW];   // [i][j]
  int tid = threadIdx.x;
  int n_base = blockIdx.x * 64;
  int tj = tid % (FOUT / 4);
  int tn = tid / (FOUT / 4);  // 0..15
  int j0 = tj * 4, n0 = tn * 4;

  float acc[4][4];
  if (mode == 0) {
    float4 b = *(const float4*)(bias + j0);
    for (int a = 0; a < 4; a++) { acc[a][0] = b.x; acc[a][1] = b.y; acc[a][2] = b.z; acc[a][3] = b.w; }
  } else {
    for (int a = 0; a < 4; a++) {
      int n = n_base + n0 + a;
      if (n < N) {
        float4 h = *(const float4*)(H + (size_t)n * FOUT + j0);
        acc[a][0] = h.x; acc[a][1] = h.y; acc[a][2] = h.z; acc[a][3] = h.w;
      } else {
        acc[a][0] = acc[a][1] = acc[a][2] = acc[a][3] = 0.f;
      }
    }
  }

  int npass = TxB ? 2 : 1;
  for (int pass = 0; pass < npass; pass++) {
    const float* Tx = pass ? TxB : TxA;
    const float* W = pass ? WB : WA;
    if (pass) __syncthreads();
    for (int idx = tid; idx < 64 * FOUT / 4; idx += blockDim.x) {
      int r = idx / (FOUT / 4), c4 = idx % (FOUT / 4);
      float4 w = *(const float4*)(W + r * FOUT + c4 * 4);
      float* p = &WS[r * PADW + c4 * 4];
      p[0] = w.x; p[1] = w.y; p[2] = w.z; p[3] = w.w;
    }
    for (int idx = tid; idx < 64 * 16; idx += blockDim.x) {
      int r = idx / 16, c4 = idx % 16;
      int n = n_base + r;
      float4 t = (n < N) ? *(const float4*)(Tx + (size_t)n * 64 + c4 * 4)
                         : make_float4(0.f, 0.f, 0.f, 0.f);
      TxT[(c4 * 4 + 0) * PADT + r] = t.x;
      TxT[(c4 * 4 + 1) * PADT + r] = t.y;
      TxT[(c4 * 4 + 2) * PADT + r] = t.z;
      TxT[(c4 * 4 + 3) * PADT + r] = t.w;
    }
    __syncthreads();
#pragma unroll 8
    for (int i = 0; i < 64; i++) {
      float4 tx = *(const float4*)(&TxT[i * PADT + n0]);
      float4 w = *(const float4*)(&WS[i * PADW + j0]);
      acc[0][0] += tx.x * w.x; acc[0][1] += tx.x * w.y; acc[0][2] += tx.x * w.z; acc[0][3] += tx.x * w.w;
      acc[1][0] += tx.y * w.x; acc[1][1] += tx.y * w.y; acc[1][2] += tx.y * w.z; acc[1][3] += tx.y * w.w;
      acc[2][0] += tx.z * w.x; acc[2][1] += tx.z * w.y; acc[2][2] += tx.z * w.z; acc[2][3] += tx.z * w.w;
      acc[3][0] += tx.w * w.x; acc[3][1] += tx.w * w.y; acc[3][2] += tx.w * w.z; acc[3][3] += tx.w * w.w;
    }
  }

  for (int a = 0; a < 4; a++) {
    int n = n_base + n0 + a;
    if (n < N)
      *(float4*)(H + (size_t)n * FOUT + j0) = make_float4(acc[a][0], acc[a][1], acc[a][2], acc[a][3]);
  }
}

// ---------------- simple combine for Fin=3 (layer 1) ----------------
__global__ void k_combine3(float* __restrict__ H, const float* __restrict__ TxA,
                           const float* __restrict__ WA, const float* __restrict__ TxB,
                           const float* __restrict__ WB, const float* __restrict__ bias,
                           int N, int mode) {
  __shared__ float wa[3 * 64], wb[3 * 64];
  int tid = threadIdx.x;
  if (tid < 192) wa[tid] = WA[tid];
  if (TxB && tid < 192) wb[tid] = WB[tid];
  __syncthreads();
  int n = blockIdx.x * 4 + tid / 64;
  int j = tid % 64;
  if (n >= N) return;
  float acc = mode ? H[n * 64 + j] : bias[j];
  for (int i = 0; i < 3; i++) acc += TxA[n * 3 + i] * wa[i * 64 + j];
  if (TxB) for (int i = 0; i < 3; i++) acc += TxB[n * 3 + i] * wb[i * 64 + j];
  H[n * 64 + j] = acc;
}

// ---------------- LeakyReLU + BN stats (float4, per-block partials) ----------------
#define BN_GRID 400
__global__ void k_bnstats(float* __restrict__ H, float* __restrict__ gpart, int N) {
  __shared__ float red[256 * 8];
  int t = threadIdx.x;
  int f4 = t & 15, r = t >> 4;
  float4* H4 = (float4*)H;
  float s0 = 0.f, s1 = 0.f, s2 = 0.f, s3 = 0.f;
  float q0 = 0.f, q1 = 0.f, q2 = 0.f, q3 = 0.f;
  for (int n = blockIdx.x * 16 + r; n < N; n += BN_GRID * 16) {
    float4 v = H4[(size_t)n * 16 + f4];
    v.x = v.x >= 0.f ? v.x : 0.01f * v.x;
    v.y = v.y >= 0.f ? v.y : 0.01f * v.y;
    v.z = v.z >= 0.f ? v.z : 0.01f * v.z;
    v.w = v.w >= 0.f ? v.w : 0.01f * v.w;
    H4[(size_t)n * 16 + f4] = v;
    s0 += v.x; s1 += v.y; s2 += v.z; s3 += v.w;
    q0 += v.x * v.x; q1 += v.y * v.y; q2 += v.z * v.z; q3 += v.w * v.w;
  }
  float* rp = &red[t * 8];
  rp[0] = s0; rp[1] = s1; rp[2] = s2; rp[3] = s3;
  rp[4] = q0; rp[5] = q1; rp[6] = q2; rp[7] = q3;
  __syncthreads();
  if (t < 64) {
    int f4g = t >> 2, k = t & 3;
    float a = 0.f, b = 0.f;
    for (int rr = 0; rr < 16; rr++) {
      a += red[(rr * 16 + f4g) * 8 + k];
      b += red[(rr * 16 + f4g) * 8 + 4 + k];
    }
    gpart[blockIdx.x * 128 + t] = a;
    gpart[blockIdx.x * 128 + 64 + t] = b;
  }
}

__global__ void k_bnfinal(const float* __restrict__ gpart, const float* __restrict__ g,
                          const float* __restrict__ bt, float* __restrict__ ab, float Ninv) {
  int t = threadIdx.x;  // 128
  float s = 0.f;
  for (int b = 0; b < BN_GRID; b++) s += gpart[b * 128 + t];
  __shared__ float red[128];
  red[t] = s; __syncthreads();
  if (t < 64) {
    float mu = red[t] * Ninv;
    float var = red[64 + t] * Ninv - mu * mu;
    float a = g[t] / sqrtf(var + EPS_BN);
    ab[t] = a;
    ab[64 + t] = bt[t] - mu * a;
  }
}

__global__ void k_bnapply(const float* __restrict__ H, const float* __restrict__ ab,
                          float* __restrict__ A, int n4) {
  int i = blockIdx.x * 256 + threadIdx.x;
  if (i >= n4) return;
  int f4 = i & 15;
  const float4* ab4 = (const float4*)ab;
  float4 sc = ab4[f4], sh = ab4[16 + f4];
  float4 v = ((const float4*)H)[i];
  v.x = v.x * sc.x + sh.x;
  v.y = v.y * sc.y + sh.y;
  v.z = v.z * sc.z + sh.z;
  v.w = v.w * sc.w + sh.w;
  ((float4*)A)[i] = v;
}

// ---------------- row L2 normalize (F=32) ----------------
__global__ void k_norm(float* __restrict__ H, int N) {
  int idx = blockIdx.x * 256 + threadIdx.x;
  int n = idx >> 5, f = idx & 31;
  if (n >= N) return;
  float v = H[n * 32 + f];
  float s = v * v;
  for (int off = 16; off; off >>= 1) s += __shfl_xor(s, off, 32);
  float nrm = sqrtf(s);
  nrm = fmaxf(nrm, 1e-12f);
  H[n * 32 + f] = v / nrm;
}

// ---------------- pooling ----------------
__device__ __forceinline__ unsigned fkey(float x) {
  unsigned u = __float_as_uint(x);
  return (u & 0x80000000u) ? ~u : (u | 0x80000000u);
}
__device__ __forceinline__ float fdec(unsigned u) {
  return (u & 0x80000000u) ? __uint_as_float(u & 0x7FFFFFFFu) : __uint_as_float(~u);
}

#define POOL_CHUNK 512
__global__ void k_pool2(const float* __restrict__ H, const int* __restrict__ batch,
                        float* __restrict__ psum, unsigned* __restrict__ pmax,
                        unsigned* __restrict__ pmin, float* __restrict__ pcnt, int N) {
  int f = threadIdx.x & 31;
  int sub = threadIdx.x >> 5;
  int n0 = blockIdx.x * POOL_CHUNK;
  int n1 = n0 + POOL_CHUNK; if (n1 > N) n1 = N;
  int curg = -1;
  float s = 0.f, mx = -3.4e38f, mn = 3.4e38f, cnt = 0.f;
  for (int n = n0 + sub; n < n1; n += 8) {
    int g = batch[n];
    if (g != curg) {
      if (curg >= 0) {
        atomicAdd(&psum[curg * 32 + f], s);
        atomicMax(&pmax[curg * 32 + f], fkey(mx));
        atomicMin(&pmin[curg * 32 + f], fkey(mn));
        if (f == 0) atomicAdd(&pcnt[curg], cnt);
      }
      curg = g; s = 0.f; mx = -3.4e38f; mn = 3.4e38f; cnt = 0.f;
    }
    float v = H[n * 32 + f];
    s += v; mx = fmaxf(mx, v); mn = fminf(mn, v); cnt += 1.f;
  }
  if (curg >= 0) {
    atomicAdd(&psum[curg * 32 + f], s);
    atomicMax(&pmax[curg * 32 + f], fkey(mx));
    atomicMin(&pmin[curg * 32 + f], fkey(mn));
    if (f == 0) atomicAdd(&pcnt[curg], cnt);
  }
}

__global__ void k_poolfin(const float* __restrict__ psum, const unsigned* __restrict__ pmax,
                          const unsigned* __restrict__ pmin, const float* __restrict__ pcnt,
                          float* __restrict__ out) {
  int g = blockIdx.x, f = threadIdx.x;
  float s = psum[g * 32 + f];
  float c = fmaxf(pcnt[g], 1.0f);
  out[g * 128 + f] = s / c;
  out[g * 128 + 32 + f] = fdec(pmax[g * 32 + f]);
  out[g * 128 + 64 + f] = fdec(pmin[g * 32 + f]);
  out[g * 128 + 96 + f] = s;
}

// ---------------- host ----------------

extern "C" void kernel_launch(void* const* d_in, const int* in_sizes, int n_in,
                              void* d_out, int out_size, void* d_ws, size_t ws_size,
                              hipStream_t stream) {
  const float* x   = (const float*)d_in[0];
  const int*   ei  = (const int*)d_in[1];
  const int*   bat = (const int*)d_in[2];
  const float* W1  = (const float*)d_in[3];  const float* bc1 = (const float*)d_in[4];
  const float* W2  = (const float*)d_in[5];  const float* bc2 = (const float*)d_in[6];
  const float* W3  = (const float*)d_in[7];  const float* bc3 = (const float*)d_in[8];
  const float* W4  = (const float*)d_in[9];  const float* bc4 = (const float*)d_in[10];
  const float* g1  = (const float*)d_in[11]; const float* bt1 = (const float*)d_in[12];
  const float* g2  = (const float*)d_in[13]; const float* bt2 = (const float*)d_in[14];
  const float* g3  = (const float*)d_in[15]; const float* bt3 = (const float*)d_in[16];

  const int N = in_sizes[0] / 3;
  const int E = in_sizes[1] / 2;
  const int* src = ei;
  const int* dst = ei + E;
  const size_t Epad = (size_t)E + (size_t)(ROWPAD - 1) * N + 64;  // upper bound on padded edges

  float* base = (float*)d_ws;
  size_t o = 0;
  auto alloc = [&](size_t n) -> float* {
    float* p = base + o;
    o += (n + 63) & ~(size_t)63;
    return p;
  };
  // zeroed region (contiguous from d_ws start):
  float* deg    = alloc(N);
  int*   hist   = (int*)alloc(N);
  int*   cursor = (int*)alloc(N);
  float* psum   = alloc(64 * 32);
  float* pcnt   = alloc(64);
  unsigned* pmax = (unsigned*)alloc(64 * 32);
  int*   ssrc  = (int*)alloc(Epad);   // zero: pad slots gather row 0
  float* sew   = alloc(Epad);         // zero: pad slots contribute 0
  size_t zero_elems = o;
  // 0xFF region:
  unsigned* pmin = (unsigned*)alloc(64 * 32);
  // uninitialized:
  int*   offs  = (int*)alloc(N + 1);
  int*   bsum  = (int*)alloc(256);
  int*   bbase = (int*)alloc(257);
  float* gpart = alloc(BN_GRID * 128);
  float* ab    = alloc(128);
  float* A     = alloc((size_t)N * 64);
  float* B     = alloc((size_t)N * 64);
  float* H     = alloc((size_t)N * 64);

  hipMemsetAsync(d_ws, 0, zero_elems * sizeof(float), stream);
  hipMemsetAsync(pmin, 0xFF, 64 * 32 * sizeof(unsigned), stream);

  const int EB = (E + 255) / 256;
  const int NB = (N + 255) / 256;
  const int SB = (N + SC_CHUNK - 1) / SC_CHUNK;

  k_deg<<<EB, 256, 0, stream>>>(src, deg, E);
  k_dinv<<<NB, 256, 0, stream>>>(deg, N);
  k_hist<<<EB, 256, 0, stream>>>(dst, hist, E);
  k_scan1<<<SB, 256, 0, stream>>>(hist, bsum, N);
  k_scan2<<<1, 256, 0, stream>>>(bsum, bbase, SB);
  k_scan3<<<SB, 256, 0, stream>>>(hist, bbase, offs, N, SB);
  k_scatter<<<EB, 256, 0, stream>>>(src, dst, deg, offs, cursor, ssrc, sew, E);

  const int PB64 = (N * 64 + 255) / 256;
  const int TB = (N + 63) / 64;

  auto comb64 = [&](const float* TxA, const float* WA, const float* TxB, const float* WB,
                    const float* bias, int mode) {
    k_combine_t<64><<<TB, 256, 0, stream>>>(H, TxA, WA, TxB, WB, bias, N, mode);
  };
  auto comb32 = [&](const float* TxA, const float* WA, const float* TxB, const float* WB,
                    const float* bias, int mode) {
    k_combine_t<32><<<TB, 128, 0, stream>>>(H, TxA, WA, TxB, WB, bias, N, mode);
  };

  // ---- layer 1: Fin=3 -> 64 ----
  {
    const float* W = W1;
    k_prop3<<<NB, 256, 0, stream>>>(x, nullptr, B, offs, ssrc, sew, N, 0);
    k_combine3<<<(N + 3) / 4, 256, 0, stream>>>(H, x, W + 0 * 192, B, W + 1 * 192, bc1, N, 0);
    k_prop3<<<NB, 256, 0, stream>>>(B, x, A, offs, ssrc, sew, N, 1);
    k_combine3<<<(N + 3) / 4, 256, 0, stream>>>(H, A, W + 2 * 192, nullptr, nullptr, nullptr, N, 1);
    k_prop3<<<NB, 256, 0, stream>>>(A, B, B, offs, ssrc, sew, N, 1);
    k_combine3<<<(N + 3) / 4, 256, 0, stream>>>(H, B, W + 3 * 192, nullptr, nullptr, nullptr, N, 1);
    k_bnstats<<<BN_GRID, 256, 0, stream>>>(H, gpart, N);
    k_bnfinal<<<1, 128, 0, stream>>>(gpart, g1, bt1, ab, 1.0f / N);
    k_bnapply<<<(N * 16 + 255) / 256, 256, 0, stream>>>(H, ab, A, N * 16);
  }

  // ---- layers 2 & 3: 64 -> 64 ----
  const float* Ws[2] = {W2, W3};
  const float* bs[2] = {bc2, bc3};
  const float* gs[2] = {g2, g3};
  const float* bts[2] = {bt2, bt3};
  for (int L = 0; L < 2; L++) {
    const float* W = Ws[L];
    k_prop64<<<PB64, 256, 0, stream>>>(A, nullptr, B, offs, ssrc, sew, N, 0);
    comb64(A, W + 0 * 4096, B, W + 1 * 4096, bs[L], 0);
    k_prop64<<<PB64, 256, 0, stream>>>(B, A, A, offs, ssrc, sew, N, 1);
    comb64(A, W + 2 * 4096, nullptr, nullptr, nullptr, 1);
    k_prop64<<<PB64, 256, 0, stream>>>(A, B, B, offs, ssrc, sew, N, 1);
    comb64(B, W + 3 * 4096, nullptr, nullptr, nullptr, 1);
    k_bnstats<<<BN_GRID, 256, 0, stream>>>(H, gpart, N);
    k_bnfinal<<<1, 128, 0, stream>>>(gpart, gs[L], bts[L], ab, 1.0f / N);
    k_bnapply<<<(N * 16 + 255) / 256, 256, 0, stream>>>(H, ab, A, N * 16);
  }

  // ---- layer 4: 64 -> 32 ----
  {
    const float* W = W4;
    k_prop64<<<PB64, 256, 0, stream>>>(A, nullptr, B, offs, ssrc, sew, N, 0);
    comb32(A, W + 0 * 2048, B, W + 1 * 2048, bc4, 0);
    k_prop64<<<PB64, 256, 0, stream>>>(B, A, A, offs, ssrc, sew, N, 1);
    comb32(A, W + 2 * 2048, nullptr, nullptr, nullptr, 1);
    k_prop64<<<PB64, 256, 0, stream>>>(A, B, B, offs, ssrc, sew, N, 1);
    comb32(B, W + 3 * 2048, nullptr, nullptr, nullptr, 1);
  }

  // ---- normalize + pool ----
  const int RB32 = (N * 32 + 255) / 256;
  k_norm<<<RB32, 256, 0, stream>>>(H, N);
  k_pool2<<<(N + POOL_CHUNK - 1) / POOL_CHUNK, 256, 0, stream>>>(H, bat, psum, pmax, pmin, pcnt, N);
  k_poolfin<<<64, 32, 0, stream>>>(psum, pmax, pmin, pcnt, (float*)d_out);
}

// Round 5
// 1267.140 us; speedup vs baseline: 2.8718x; 1.0580x over previous
//
#include <hip/hip_runtime.h>

#define EPS_BN 1e-5f
#define ROWPAD 8  // CSR rows padded to multiple of 8 edges (src=0,w=0 filler)

// ---------------- preprocessing ----------------

__global__ void k_deghist(const int* __restrict__ src, const int* __restrict__ dst,
                          float* __restrict__ deg, int* __restrict__ hist, int E) {
  int e = blockIdx.x * 256 + threadIdx.x;
  if (e < E) {
    atomicAdd(&deg[src[e]], 1.0f);
    atomicAdd(&hist[dst[e]], 1);
  }
}

__global__ void k_dinv(float* __restrict__ deg, int N) {
  int i = blockIdx.x * 256 + threadIdx.x;
  if (i < N) { float d = deg[i]; deg[i] = d > 0.f ? 1.0f / sqrtf(d) : 0.f; }
}

// ---- hierarchical scan over PADDED counts ----
#define SC_CHUNK 400

__device__ __forceinline__ int lds_incl_scan256(int* lds, int t, int v) {
  lds[t] = v; __syncthreads();
  for (int off = 1; off < 256; off <<= 1) {
    int u = (t >= off) ? lds[t - off] : 0;
    __syncthreads();
    lds[t] += u;
    __syncthreads();
  }
  return lds[t];
}

__device__ __forceinline__ int padcnt(int h) { return (h + (ROWPAD - 1)) & ~(ROWPAD - 1); }

__global__ void k_scan1(const int* __restrict__ hist, int* __restrict__ bsum, int N) {
  __shared__ int lds[256];
  int b = blockIdx.x, t = threadIdx.x;
  int lo = b * SC_CHUNK;
  int hi = lo + SC_CHUNK; if (hi > N) hi = N;
  int i0 = lo + t * 2;
  int s = 0;
  if (i0 < hi) s += padcnt(hist[i0]);
  if (i0 + 1 < hi) s += padcnt(hist[i0 + 1]);
  int incl = lds_incl_scan256(lds, t, s);
  if (t == 255) bsum[b] = incl;
}

__global__ void k_scan2(const int* __restrict__ bsum, int* __restrict__ bbase, int nb) {
  __shared__ int lds[256];
  int t = threadIdx.x;
  int v = (t < nb) ? bsum[t] : 0;
  int incl = lds_incl_scan256(lds, t, v);
  if (t < nb) bbase[t] = incl - v;
  if (t == nb - 1) bbase[nb] = incl;
}

__global__ void k_scan3(const int* __restrict__ hist, const int* __restrict__ bbase,
                        int* __restrict__ offs, int N, int nb) {
  __shared__ int lds[256];
  int b = blockIdx.x, t = threadIdx.x;
  int lo = b * SC_CHUNK;
  int hi = lo + SC_CHUNK; if (hi > N) hi = N;
  int i0 = lo + t * 2;
  int h0 = (i0 < hi) ? padcnt(hist[i0]) : 0;
  int h1 = (i0 + 1 < hi) ? padcnt(hist[i0 + 1]) : 0;
  int s = h0 + h1;
  int incl = lds_incl_scan256(lds, t, s);
  int run = bbase[b] + incl - s;
  if (i0 < hi) offs[i0] = run;
  if (i0 + 1 < hi) offs[i0 + 1] = run + h0;
  if (b == 0 && t == 0) offs[N] = bbase[nb];
}

// scatter interleaved (src, weight-bits) records: one 8B store per edge
__global__ void k_scatter(const int* __restrict__ src, const int* __restrict__ dst,
                          const float* __restrict__ dinv, const int* __restrict__ offs,
                          int* __restrict__ cursor, int2* __restrict__ erec, int E) {
  int e = blockIdx.x * 256 + threadIdx.x;
  if (e >= E) return;
  int s = src[e], d = dst[e];
  int pos = offs[d] + atomicAdd(&cursor[d], 1);
  int2 r;
  r.x = s;
  r.y = __float_as_int(-dinv[s] * dinv[d]);
  erec[pos] = r;
}

// ---------------- propagation (padded CSR, 16-wide MLP) ----------------
// out = gab? a*acc + b*sw : acc ; recur: out = 2*out - affine(oldv)
__global__ void k_prop64(const float* __restrict__ gf, const float* __restrict__ gab,
                         const float* __restrict__ oldv, const float* __restrict__ oab,
                         float* __restrict__ outv, const int* __restrict__ offs,
                         const int4* __restrict__ erec4, int N, int recur) {
  int wid = (blockIdx.x * 256 + threadIdx.x) >> 6;
  int lane = threadIdx.x & 63;
  if (wid >= N) return;
  int q = offs[wid] >> 1, qe = offs[wid + 1] >> 1;  // int4 units (2 records each)
  float acc = 0.f, sw = 0.f;
  for (; q + 8 <= qe; q += 8) {  // 16 records
    int4 m[8];
#pragma unroll
    for (int j = 0; j < 8; j++) m[j] = erec4[q + j];
    float g[16];
#pragma unroll
    for (int j = 0; j < 8; j++) {
      g[2 * j]     = gf[(size_t)m[j].x * 64 + lane];
      g[2 * j + 1] = gf[(size_t)m[j].z * 64 + lane];
    }
#pragma unroll
    for (int j = 0; j < 8; j++) {
      float w0 = __int_as_float(m[j].y), w1 = __int_as_float(m[j].w);
      acc += w0 * g[2 * j] + w1 * g[2 * j + 1];
      sw += w0 + w1;
    }
  }
  if (q < qe) {  // exactly 8 records
    int4 m[4];
#pragma unroll
    for (int j = 0; j < 4; j++) m[j] = erec4[q + j];
    float g[8];
#pragma unroll
    for (int j = 0; j < 4; j++) {
      g[2 * j]     = gf[(size_t)m[j].x * 64 + lane];
      g[2 * j + 1] = gf[(size_t)m[j].z * 64 + lane];
    }
#pragma unroll
    for (int j = 0; j < 4; j++) {
      float w0 = __int_as_float(m[j].y), w1 = __int_as_float(m[j].w);
      acc += w0 * g[2 * j] + w1 * g[2 * j + 1];
      sw += w0 + w1;
    }
  }
  float res = acc;
  if (gab) res = gab[lane] * acc + gab[64 + lane] * sw;
  int idx = wid * 64 + lane;
  if (recur) {
    float o = oldv[idx];
    if (oab) o = oab[lane] * o + oab[64 + lane];
    res = 2.f * res - o;
  }
  outv[idx] = res;
}

__global__ void k_prop3(const float* __restrict__ gf, const float* __restrict__ oldv,
                        float* __restrict__ outv, const int* __restrict__ offs,
                        const int4* __restrict__ erec4, int N, int recur) {
  int n = blockIdx.x * 256 + threadIdx.x;
  if (n >= N) return;
  int q = offs[n] >> 1, qe = offs[n + 1] >> 1;
  float a0 = 0.f, a1 = 0.f, a2 = 0.f;
  for (; q < qe; q += 4) {  // 8 records per iter; rows are multiples of 4 int4s
    int4 m[4];
#pragma unroll
    for (int j = 0; j < 4; j++) m[j] = erec4[q + j];
#pragma unroll
    for (int j = 0; j < 4; j++) {
      float w0 = __int_as_float(m[j].y), w1 = __int_as_float(m[j].w);
      int s0 = m[j].x, s1 = m[j].z;
      a0 += w0 * gf[s0 * 3 + 0] + w1 * gf[s1 * 3 + 0];
      a1 += w0 * gf[s0 * 3 + 1] + w1 * gf[s1 * 3 + 1];
      a2 += w0 * gf[s0 * 3 + 2] + w1 * gf[s1 * 3 + 2];
    }
  }
  if (recur) {
    a0 = 2.f * a0 - oldv[n * 3 + 0];
    a1 = 2.f * a1 - oldv[n * 3 + 1];
    a2 = 2.f * a2 - oldv[n * 3 + 2];
  }
  outv[n * 3 + 0] = a0;
  outv[n * 3 + 1] = a1;
  outv[n * 3 + 2] = a2;
}

// ---------------- tiled combine: H = [bias|H] + TxA@WA (+TxB@WB) ----------------
// abA != null: apply per-feature affine to TxA while staging (Tx0 = a*h+b).
// In-place safe (H may alias TxA/TxB): each block reads/writes only its own tile.
template <int FOUT>
__global__ void k_combine_t(float* H, const float* TxA,
                            const float* __restrict__ WA, const float* TxB,
                            const float* __restrict__ WB, const float* __restrict__ bias,
                            const float* __restrict__ abA, int N, int mode) {
  constexpr int PADT = 68;
  constexpr int PADW = FOUT + 4;
  __shared__ float TxT[64 * PADT];
  __shared__ float WS[64 * PADW];
  int tid = threadIdx.x;
  int n_base = blockIdx.x * 64;
  int tj = tid % (FOUT / 4);
  int tn = tid / (FOUT / 4);
  int j0 = tj * 4, n0 = tn * 4;

  float acc[4][4];
  if (mode == 0) {
    float4 b = *(const float4*)(bias + j0);
    for (int a = 0; a < 4; a++) { acc[a][0] = b.x; acc[a][1] = b.y; acc[a][2] = b.z; acc[a][3] = b.w; }
  } else {
    for (int a = 0; a < 4; a++) {
      int n = n_base + n0 + a;
      if (n < N) {
        float4 h = *(const float4*)(H + (size_t)n * FOUT + j0);
        acc[a][0] = h.x; acc[a][1] = h.y; acc[a][2] = h.z; acc[a][3] = h.w;
      } else {
        acc[a][0] = acc[a][1] = acc[a][2] = acc[a][3] = 0.f;
      }
    }
  }

  int npass = TxB ? 2 : 1;
  for (int pass = 0; pass < npass; pass++) {
    const float* Tx = pass ? TxB : TxA;
    const float* W = pass ? WB : WA;
    if (pass) __syncthreads();
    for (int idx = tid; idx < 64 * FOUT / 4; idx += blockDim.x) {
      int r = idx / (FOUT / 4), c4 = idx % (FOUT / 4);
      float4 w = *(const float4*)(W + r * FOUT + c4 * 4);
      float* p = &WS[r * PADW + c4 * 4];
      p[0] = w.x; p[1] = w.y; p[2] = w.z; p[3] = w.w;
    }
    for (int idx = tid; idx < 64 * 16; idx += blockDim.x) {
      int r = idx / 16, c4 = idx % 16;
      int n = n_base + r;
      float4 t = (n < N) ? *(const float4*)(Tx + (size_t)n * 64 + c4 * 4)
                         : make_float4(0.f, 0.f, 0.f, 0.f);
      if (pass == 0 && abA) {
        float4 a4 = *(const float4*)(abA + c4 * 4);
        float4 b4 = *(const float4*)(abA + 64 + c4 * 4);
        t.x = t.x * a4.x + b4.x;
        t.y = t.y * a4.y + b4.y;
        t.z = t.z * a4.z + b4.z;
        t.w = t.w * a4.w + b4.w;
      }
      TxT[(c4 * 4 + 0) * PADT + r] = t.x;
      TxT[(c4 * 4 + 1) * PADT + r] = t.y;
      TxT[(c4 * 4 + 2) * PADT + r] = t.z;
      TxT[(c4 * 4 + 3) * PADT + r] = t.w;
    }
    __syncthreads();
#pragma unroll 8
    for (int i = 0; i < 64; i++) {
      float4 tx = *(const float4*)(&TxT[i * PADT + n0]);
      float4 w = *(const float4*)(&WS[i * PADW + j0]);
      acc[0][0] += tx.x * w.x; acc[0][1] += tx.x * w.y; acc[0][2] += tx.x * w.z; acc[0][3] += tx.x * w.w;
      acc[1][0] += tx.y * w.x; acc[1][1] += tx.y * w.y; acc[1][2] += tx.y * w.z; acc[1][3] += tx.y * w.w;
      acc[2][0] += tx.z * w.x; acc[2][1] += tx.z * w.y; acc[2][2] += tx.z * w.z; acc[2][3] += tx.z * w.w;
      acc[3][0] += tx.w * w.x; acc[3][1] += tx.w * w.y; acc[3][2] += tx.w * w.z; acc[3][3] += tx.w * w.w;
    }
  }

  for (int a = 0; a < 4; a++) {
    int n = n_base + n0 + a;
    if (n < N)
      *(float4*)(H + (size_t)n * FOUT + j0) = make_float4(acc[a][0], acc[a][1], acc[a][2], acc[a][3]);
  }
}

// ---------------- simple combine for Fin=3 (layer 1) ----------------
__global__ void k_combine3(float* __restrict__ H, const float* __restrict__ TxA,
                           const float* __restrict__ WA, const float* __restrict__ TxB,
                           const float* __restrict__ WB, const float* __restrict__ bias,
                           int N, int mode) {
  __shared__ float wa[3 * 64], wb[3 * 64];
  int tid = threadIdx.x;
  if (tid < 192) wa[tid] = WA[tid];
  if (TxB && tid < 192) wb[tid] = WB[tid];
  __syncthreads();
  int n = blockIdx.x * 4 + tid / 64;
  int j = tid % 64;
  if (n >= N) return;
  float acc = mode ? H[n * 64 + j] : bias[j];
  for (int i = 0; i < 3; i++) acc += TxA[n * 3 + i] * wa[i * 64 + j];
  if (TxB) for (int i = 0; i < 3; i++) acc += TxB[n * 3 + i] * wb[i * 64 + j];
  H[n * 64 + j] = acc;
}

// ---------------- LeakyReLU + BN stats (float4, per-block partials) ----------------
#define BN_GRID 400
__global__ void k_bnstats(float* __restrict__ H, float* __restrict__ gpart, int N) {
  __shared__ float red[256 * 8];
  int t = threadIdx.x;
  int f4 = t & 15, r = t >> 4;
  float4* H4 = (float4*)H;
  float s0 = 0.f, s1 = 0.f, s2 = 0.f, s3 = 0.f;
  float q0 = 0.f, q1 = 0.f, q2 = 0.f, q3 = 0.f;
  for (int n = blockIdx.x * 16 + r; n < N; n += BN_GRID * 16) {
    float4 v = H4[(size_t)n * 16 + f4];
    v.x = v.x >= 0.f ? v.x : 0.01f * v.x;
    v.y = v.y >= 0.f ? v.y : 0.01f * v.y;
    v.z = v.z >= 0.f ? v.z : 0.01f * v.z;
    v.w = v.w >= 0.f ? v.w : 0.01f * v.w;
    H4[(size_t)n * 16 + f4] = v;
    s0 += v.x; s1 += v.y; s2 += v.z; s3 += v.w;
    q0 += v.x * v.x; q1 += v.y * v.y; q2 += v.z * v.z; q3 += v.w * v.w;
  }
  float* rp = &red[t * 8];
  rp[0] = s0; rp[1] = s1; rp[2] = s2; rp[3] = s3;
  rp[4] = q0; rp[5] = q1; rp[6] = q2; rp[7] = q3;
  __syncthreads();
  if (t < 64) {
    int f4g = t >> 2, k = t & 3;
    float a = 0.f, b = 0.f;
    for (int rr = 0; rr < 16; rr++) {
      a += red[(rr * 16 + f4g) * 8 + k];
      b += red[(rr * 16 + f4g) * 8 + 4 + k];
    }
    gpart[blockIdx.x * 128 + t] = a;
    gpart[blockIdx.x * 128 + 64 + t] = b;
  }
}

__global__ void k_bnfinal(const float* __restrict__ gpart, const float* __restrict__ g,
                          const float* __restrict__ bt, float* __restrict__ ab, float Ninv) {
  int t = threadIdx.x;  // 128
  float s = 0.f;
  for (int b = 0; b < BN_GRID; b++) s += gpart[b * 128 + t];
  __shared__ float red[128];
  red[t] = s; __syncthreads();
  if (t < 64) {
    float mu = red[t] * Ninv;
    float var = red[64 + t] * Ninv - mu * mu;
    float a = g[t] / sqrtf(var + EPS_BN);
    ab[t] = a;
    ab[64 + t] = bt[t] - mu * a;
  }
}

// ---------------- pooling (fused row L2-normalize) ----------------
__device__ __forceinline__ unsigned fkey(float x) {
  unsigned u = __float_as_uint(x);
  return (u & 0x80000000u) ? ~u : (u | 0x80000000u);
}
__device__ __forceinline__ float fdec(unsigned u) {
  return (u & 0x80000000u) ? __uint_as_float(u & 0x7FFFFFFFu) : __uint_as_float(~u);
}

#define POOL_CHUNK 512
__global__ void k_pool2(const float* __restrict__ H, const int* __restrict__ batch,
                        float* __restrict__ psum, unsigned* __restrict__ pmax,
                        unsigned* __restrict__ pmin, float* __restrict__ pcnt, int N) {
  int f = threadIdx.x & 31;
  int sub = threadIdx.x >> 5;
  int n0 = blockIdx.x * POOL_CHUNK;
  int n1 = n0 + POOL_CHUNK; if (n1 > N) n1 = N;
  int curg = -1;
  float s = 0.f, mx = -3.4e38f, mn = 3.4e38f, cnt = 0.f;
  for (int n = n0 + sub; n < n1; n += 8) {
    int g = batch[n];
    if (g != curg) {
      if (curg >= 0) {
        atomicAdd(&psum[curg * 32 + f], s);
        atomicMax(&pmax[curg * 32 + f], fkey(mx));
        atomicMin(&pmin[curg * 32 + f], fkey(mn));
        if (f == 0) atomicAdd(&pcnt[curg], cnt);
      }
      curg = g; s = 0.f; mx = -3.4e38f; mn = 3.4e38f; cnt = 0.f;
    }
    float v = H[n * 32 + f];
    float ss = v * v;
    for (int off = 16; off; off >>= 1) ss += __shfl_xor(ss, off, 32);
    v /= fmaxf(sqrtf(ss), 1e-12f);
    s += v; mx = fmaxf(mx, v); mn = fminf(mn, v); cnt += 1.f;
  }
  if (curg >= 0) {
    atomicAdd(&psum[curg * 32 + f], s);
    atomicMax(&pmax[curg * 32 + f], fkey(mx));
    atomicMin(&pmin[curg * 32 + f], fkey(mn));
    if (f == 0) atomicAdd(&pcnt[curg], cnt);
  }
}

__global__ void k_poolfin(const float* __restrict__ psum, const unsigned* __restrict__ pmax,
                          const unsigned* __restrict__ pmin, const float* __restrict__ pcnt,
                          float* __restrict__ out) {
  int g = blockIdx.x, f = threadIdx.x;
  float s = psum[g * 32 + f];
  float c = fmaxf(pcnt[g], 1.0f);
  out[g * 128 + f] = s / c;
  out[g * 128 + 32 + f] = fdec(pmax[g * 32 + f]);
  out[g * 128 + 64 + f] = fdec(pmin[g * 32 + f]);
  out[g * 128 + 96 + f] = s;
}

// ---------------- host ----------------

extern "C" void kernel_launch(void* const* d_in, const int* in_sizes, int n_in,
                              void* d_out, int out_size, void* d_ws, size_t ws_size,
                              hipStream_t stream) {
  const float* x   = (const float*)d_in[0];
  const int*   ei  = (const int*)d_in[1];
  const int*   bat = (const int*)d_in[2];
  const float* W1  = (const float*)d_in[3];  const float* bc1 = (const float*)d_in[4];
  const float* W2  = (const float*)d_in[5];  const float* bc2 = (const float*)d_in[6];
  const float* W3  = (const float*)d_in[7];  const float* bc3 = (const float*)d_in[8];
  const float* W4  = (const float*)d_in[9];  const float* bc4 = (const float*)d_in[10];
  const float* g1  = (const float*)d_in[11]; const float* bt1 = (const float*)d_in[12];
  const float* g2  = (const float*)d_in[13]; const float* bt2 = (const float*)d_in[14];
  const float* g3  = (const float*)d_in[15]; const float* bt3 = (const float*)d_in[16];

  const int N = in_sizes[0] / 3;
  const int E = in_sizes[1] / 2;
  const int* src = ei;
  const int* dst = ei + E;
  const size_t Epad = (size_t)E + (size_t)(ROWPAD - 1) * N + 64;

  float* base = (float*)d_ws;
  size_t o = 0;
  auto alloc = [&](size_t n) -> float* {
    float* p = base + o;
    o += (n + 63) & ~(size_t)63;
    return p;
  };
  // zeroed region (contiguous from d_ws start):
  float* deg    = alloc(N);
  int*   hist   = (int*)alloc(N);
  int*   cursor = (int*)alloc(N);
  float* psum   = alloc(64 * 32);
  float* pcnt   = alloc(64);
  unsigned* pmax = (unsigned*)alloc(64 * 32);
  int2*  erec  = (int2*)alloc(2 * Epad);  // zero: pad slots = {src 0, w 0}
  size_t zero_elems = o;
  // 0xFF region:
  unsigned* pmin = (unsigned*)alloc(64 * 32);
  // uninitialized:
  int*   offs  = (int*)alloc(N + 1);
  int*   bsum  = (int*)alloc(256);
  int*   bbase = (int*)alloc(257);
  float* gpart = alloc(BN_GRID * 128);
  float* ab    = alloc(128);
  float* A     = alloc((size_t)N * 64);
  float* B     = alloc((size_t)N * 64);
  float* H     = alloc((size_t)N * 64);
  float* C32   = alloc((size_t)N * 32);

  hipMemsetAsync(d_ws, 0, zero_elems * sizeof(float), stream);
  hipMemsetAsync(pmin, 0xFF, 64 * 32 * sizeof(unsigned), stream);

  const int EB = (E + 255) / 256;
  const int NB = (N + 255) / 256;
  const int SB = (N + SC_CHUNK - 1) / SC_CHUNK;

  k_deghist<<<EB, 256, 0, stream>>>(src, dst, deg, hist, E);
  k_dinv<<<NB, 256, 0, stream>>>(deg, N);
  k_scan1<<<SB, 256, 0, stream>>>(hist, bsum, N);
  k_scan2<<<1, 256, 0, stream>>>(bsum, bbase, SB);
  k_scan3<<<SB, 256, 0, stream>>>(hist, bbase, offs, N, SB);
  k_scatter<<<EB, 256, 0, stream>>>(src, dst, deg, offs, cursor, erec, E);

  const int PB64 = (N * 64 + 255) / 256;
  const int TB = (N + 63) / 64;
  const int4* erec4 = (const int4*)erec;

  // ---- layer 1: Fin=3 -> 64 ----
  {
    const float* W = W1;
    k_prop3<<<NB, 256, 0, stream>>>(x, nullptr, B, offs, erec4, N, 0);
    k_combine3<<<(N + 3) / 4, 256, 0, stream>>>(H, x, W + 0 * 192, B, W + 1 * 192, bc1, N, 0);
    k_prop3<<<NB, 256, 0, stream>>>(B, x, A, offs, erec4, N, 1);
    k_combine3<<<(N + 3) / 4, 256, 0, stream>>>(H, A, W + 2 * 192, nullptr, nullptr, nullptr, N, 1);
    k_prop3<<<NB, 256, 0, stream>>>(A, B, B, offs, erec4, N, 1);
    k_combine3<<<(N + 3) / 4, 256, 0, stream>>>(H, B, W + 3 * 192, nullptr, nullptr, nullptr, N, 1);
    k_bnstats<<<BN_GRID, 256, 0, stream>>>(H, gpart, N);
    k_bnfinal<<<1, 128, 0, stream>>>(gpart, g1, bt1, ab, 1.0f / N);
  }

  // ---- layers 2 & 3: 64 -> 64 (Tx0 = ab∘H virtual; combine in-place on H) ----
  const float* Ws[2] = {W2, W3};
  const float* bs[2] = {bc2, bc3};
  const float* gs[2] = {g2, g3};
  const float* bts[2] = {bt2, bt3};
  for (int L = 0; L < 2; L++) {
    const float* W = Ws[L];
    // B = L · (ab∘H)
    k_prop64<<<PB64, 256, 0, stream>>>(H, ab, nullptr, nullptr, B, offs, erec4, N, 0);
    // A = 2·L·B − (ab∘H)
    k_prop64<<<PB64, 256, 0, stream>>>(B, nullptr, H, ab, A, offs, erec4, N, 1);
    // H = bias + (ab∘H)@W0 + B@W1   (in-place, tile-local)
    k_combine_t<64><<<TB, 256, 0, stream>>>(H, H, W + 0 * 4096, B, W + 1 * 4096, bs[L], ab, N, 0);
    // H += A@W2
    k_combine_t<64><<<TB, 256, 0, stream>>>(H, A, W + 2 * 4096, nullptr, nullptr, nullptr, nullptr, N, 1);
    // B = 2·L·A − B
    k_prop64<<<PB64, 256, 0, stream>>>(A, nullptr, B, nullptr, B, offs, erec4, N, 1);
    // H += B@W3
    k_combine_t<64><<<TB, 256, 0, stream>>>(H, B, W + 3 * 4096, nullptr, nullptr, nullptr, nullptr, N, 1);
    k_bnstats<<<BN_GRID, 256, 0, stream>>>(H, gpart, N);
    k_bnfinal<<<1, 128, 0, stream>>>(gpart, gs[L], bts[L], ab, 1.0f / N);
  }

  // ---- layer 4: 64 -> 32 (output C32) ----
  {
    const float* W = W4;
    k_prop64<<<PB64, 256, 0, stream>>>(H, ab, nullptr, nullptr, B, offs, erec4, N, 0);
    k_prop64<<<PB64, 256, 0, stream>>>(B, nullptr, H, ab, A, offs, erec4, N, 1);
    k_combine_t<32><<<TB, 128, 0, stream>>>(C32, H, W + 0 * 2048, B, W + 1 * 2048, bc4, ab, N, 0);
    k_combine_t<32><<<TB, 128, 0, stream>>>(C32, A, W + 2 * 2048, nullptr, nullptr, nullptr, nullptr, N, 1);
    k_prop64<<<PB64, 256, 0, stream>>>(A, nullptr, B, nullptr, B, offs, erec4, N, 1);
    k_combine_t<32><<<TB, 128, 0, stream>>>(C32, B, W + 3 * 2048, nullptr, nullptr, nullptr, nullptr, N, 1);
  }

  // ---- pool (L2-normalize fused) ----
  k_pool2<<<(N + POOL_CHUNK - 1) / POOL_CHUNK, 256, 0, stream>>>(C32, bat, psum, pmax, pmin, pcnt, N);
  k_poolfin<<<64, 32, 0, stream>>>(psum, pmax, pmin, pcnt, (float*)d_out);
}

// Round 6
// 1250.962 us; speedup vs baseline: 2.9089x; 1.0129x over previous
//
#include <hip/hip_runtime.h>

#define EPS_BN 1e-5f
#define ROWPAD 8   // CSR rows padded to multiple of 8 edges (src=0,w=0 filler)
#define HSEG 16128 // histogram bins per segment (LDS = 63 KB)
#define HC 16      // histogram edge-chunks

// ---------------- preprocessing: LDS-privatized segmented histograms ----------------
// grid (S, HC, 2): z=0 counts src into partial[0..HC), z=1 counts dst into partial[HC..2HC)
__global__ void k_histseg(const int* __restrict__ src, const int* __restrict__ dst,
                          int* __restrict__ partial, int E, int SP) {
  __shared__ int bins[HSEG];
  int s = blockIdx.x, c = blockIdx.y, z = blockIdx.z;
  int t = threadIdx.x;
  for (int i = t; i < HSEG; i += 256) bins[i] = 0;
  __syncthreads();
  const int* keys = z ? dst : src;
  int lo = s * HSEG;
  int ck = (E + HC - 1) / HC;
  int e0 = c * ck, e1 = e0 + ck; if (e1 > E) e1 = E;
  for (int e = e0 + t; e < e1; e += 256) {
    int k = keys[e] - lo;
    if ((unsigned)k < (unsigned)HSEG) atomicAdd(&bins[k], 1);
  }
  __syncthreads();
  int* out = partial + ((size_t)(z * HC + c)) * SP + lo;
  for (int i = t; i < HSEG; i += 256) out[i] = bins[i];
}

// reduce partials -> dinv (float) + hist (int)
__global__ void k_histred(const int* __restrict__ partial, float* __restrict__ dinv,
                          int* __restrict__ hist, int N, int SP) {
  int n = blockIdx.x * 256 + threadIdx.x;
  if (n >= N) return;
  int a = 0, b = 0;
  for (int c = 0; c < HC; c++) {
    a += partial[(size_t)c * SP + n];
    b += partial[(size_t)(HC + c) * SP + n];
  }
  dinv[n] = a > 0 ? rsqrtf((float)a) : 0.f;
  hist[n] = b;
}

// ---- hierarchical scan over PADDED counts ----
#define SC_CHUNK 400

__device__ __forceinline__ int lds_incl_scan256(int* lds, int t, int v) {
  lds[t] = v; __syncthreads();
  for (int off = 1; off < 256; off <<= 1) {
    int u = (t >= off) ? lds[t - off] : 0;
    __syncthreads();
    lds[t] += u;
    __syncthreads();
  }
  return lds[t];
}

__device__ __forceinline__ int padcnt(int h) { return (h + (ROWPAD - 1)) & ~(ROWPAD - 1); }

__global__ void k_scan1(const int* __restrict__ hist, int* __restrict__ bsum, int N) {
  __shared__ int lds[256];
  int b = blockIdx.x, t = threadIdx.x;
  int lo = b * SC_CHUNK;
  int hi = lo + SC_CHUNK; if (hi > N) hi = N;
  int i0 = lo + t * 2;
  int s = 0;
  if (i0 < hi) s += padcnt(hist[i0]);
  if (i0 + 1 < hi) s += padcnt(hist[i0 + 1]);
  int incl = lds_incl_scan256(lds, t, s);
  if (t == 255) bsum[b] = incl;
}

__global__ void k_scan2(const int* __restrict__ bsum, int* __restrict__ bbase, int nb) {
  __shared__ int lds[256];
  int t = threadIdx.x;
  int v = (t < nb) ? bsum[t] : 0;
  int incl = lds_incl_scan256(lds, t, v);
  if (t < nb) bbase[t] = incl - v;
  if (t == nb - 1) bbase[nb] = incl;
}

__global__ void k_scan3(const int* __restrict__ hist, const int* __restrict__ bbase,
                        int* __restrict__ offs, int N, int nb) {
  __shared__ int lds[256];
  int b = blockIdx.x, t = threadIdx.x;
  int lo = b * SC_CHUNK;
  int hi = lo + SC_CHUNK; if (hi > N) hi = N;
  int i0 = lo + t * 2;
  int h0 = (i0 < hi) ? padcnt(hist[i0]) : 0;
  int h1 = (i0 + 1 < hi) ? padcnt(hist[i0 + 1]) : 0;
  int s = h0 + h1;
  int incl = lds_incl_scan256(lds, t, s);
  int run = bbase[b] + incl - s;
  if (i0 < hi) offs[i0] = run;
  if (i0 + 1 < hi) offs[i0 + 1] = run + h0;
  if (b == 0 && t == 0) offs[N] = bbase[nb];
}

// scatter interleaved (src, weight-bits) records: one 8B store per edge
__global__ void k_scatter(const int* __restrict__ src, const int* __restrict__ dst,
                          const float* __restrict__ dinv, const int* __restrict__ offs,
                          int* __restrict__ cursor, int2* __restrict__ erec, int E) {
  int e = blockIdx.x * 256 + threadIdx.x;
  if (e >= E) return;
  int s = src[e], d = dst[e];
  int pos = offs[d] + atomicAdd(&cursor[d], 1);
  int2 r;
  r.x = s;
  r.y = __float_as_int(-dinv[s] * dinv[d]);
  erec[pos] = r;
}

// ---------------- propagation (padded CSR, 16-wide MLP) ----------------
__global__ void k_prop64(const float* __restrict__ gf, const float* __restrict__ gab,
                         const float* __restrict__ oldv, const float* __restrict__ oab,
                         float* __restrict__ outv, const int* __restrict__ offs,
                         const int4* __restrict__ erec4, int N, int recur) {
  int wid = (blockIdx.x * 256 + threadIdx.x) >> 6;
  int lane = threadIdx.x & 63;
  if (wid >= N) return;
  int q = offs[wid] >> 1, qe = offs[wid + 1] >> 1;  // int4 units (2 records each)
  float acc = 0.f, sw = 0.f;
  for (; q + 8 <= qe; q += 8) {  // 16 records
    int4 m[8];
#pragma unroll
    for (int j = 0; j < 8; j++) m[j] = erec4[q + j];
    float g[16];
#pragma unroll
    for (int j = 0; j < 8; j++) {
      g[2 * j]     = gf[(size_t)m[j].x * 64 + lane];
      g[2 * j + 1] = gf[(size_t)m[j].z * 64 + lane];
    }
#pragma unroll
    for (int j = 0; j < 8; j++) {
      float w0 = __int_as_float(m[j].y), w1 = __int_as_float(m[j].w);
      acc += w0 * g[2 * j] + w1 * g[2 * j + 1];
      sw += w0 + w1;
    }
  }
  if (q < qe) {  // exactly 8 records
    int4 m[4];
#pragma unroll
    for (int j = 0; j < 4; j++) m[j] = erec4[q + j];
    float g[8];
#pragma unroll
    for (int j = 0; j < 4; j++) {
      g[2 * j]     = gf[(size_t)m[j].x * 64 + lane];
      g[2 * j + 1] = gf[(size_t)m[j].z * 64 + lane];
    }
#pragma unroll
    for (int j = 0; j < 4; j++) {
      float w0 = __int_as_float(m[j].y), w1 = __int_as_float(m[j].w);
      acc += w0 * g[2 * j] + w1 * g[2 * j + 1];
      sw += w0 + w1;
    }
  }
  float res = acc;
  if (gab) res = gab[lane] * acc + gab[64 + lane] * sw;
  int idx = wid * 64 + lane;
  if (recur) {
    float o = oldv[idx];
    if (oab) o = oab[lane] * o + oab[64 + lane];
    res = 2.f * res - o;
  }
  outv[idx] = res;
}

__global__ void k_prop3(const float* __restrict__ gf, const float* __restrict__ oldv,
                        float* __restrict__ outv, const int* __restrict__ offs,
                        const int4* __restrict__ erec4, int N, int recur) {
  int n = blockIdx.x * 256 + threadIdx.x;
  if (n >= N) return;
  int q = offs[n] >> 1, qe = offs[n + 1] >> 1;
  float a0 = 0.f, a1 = 0.f, a2 = 0.f;
  for (; q < qe; q += 4) {
    int4 m[4];
#pragma unroll
    for (int j = 0; j < 4; j++) m[j] = erec4[q + j];
#pragma unroll
    for (int j = 0; j < 4; j++) {
      float w0 = __int_as_float(m[j].y), w1 = __int_as_float(m[j].w);
      int s0 = m[j].x, s1 = m[j].z;
      a0 += w0 * gf[s0 * 3 + 0] + w1 * gf[s1 * 3 + 0];
      a1 += w0 * gf[s0 * 3 + 1] + w1 * gf[s1 * 3 + 1];
      a2 += w0 * gf[s0 * 3 + 2] + w1 * gf[s1 * 3 + 2];
    }
  }
  if (recur) {
    a0 = 2.f * a0 - oldv[n * 3 + 0];
    a1 = 2.f * a1 - oldv[n * 3 + 1];
    a2 = 2.f * a2 - oldv[n * 3 + 2];
  }
  outv[n * 3 + 0] = a0;
  outv[n * 3 + 1] = a1;
  outv[n * 3 + 2] = a2;
}

// ---------------- tiled combine: H = [bias|H] + TxA@WA (+TxB@WB) ----------------
template <int FOUT>
__global__ void k_combine_t(float* H, const float* TxA,
                            const float* __restrict__ WA, const float* TxB,
                            const float* __restrict__ WB, const float* __restrict__ bias,
                            const float* __restrict__ abA, int N, int mode) {
  constexpr int PADT = 68;
  constexpr int PADW = FOUT + 4;
  __shared__ float TxT[64 * PADT];
  __shared__ float WS[64 * PADW];
  int tid = threadIdx.x;
  int n_base = blockIdx.x * 64;
  int tj = tid % (FOUT / 4);
  int tn = tid / (FOUT / 4);
  int j0 = tj * 4, n0 = tn * 4;

  float acc[4][4];
  if (mode == 0) {
    float4 b = *(const float4*)(bias + j0);
    for (int a = 0; a < 4; a++) { acc[a][0] = b.x; acc[a][1] = b.y; acc[a][2] = b.z; acc[a][3] = b.w; }
  } else {
    for (int a = 0; a < 4; a++) {
      int n = n_base + n0 + a;
      if (n < N) {
        float4 h = *(const float4*)(H + (size_t)n * FOUT + j0);
        acc[a][0] = h.x; acc[a][1] = h.y; acc[a][2] = h.z; acc[a][3] = h.w;
      } else {
        acc[a][0] = acc[a][1] = acc[a][2] = acc[a][3] = 0.f;
      }
    }
  }

  int npass = TxB ? 2 : 1;
  for (int pass = 0; pass < npass; pass++) {
    const float* Tx = pass ? TxB : TxA;
    const float* W = pass ? WB : WA;
    if (pass) __syncthreads();
    for (int idx = tid; idx < 64 * FOUT / 4; idx += blockDim.x) {
      int r = idx / (FOUT / 4), c4 = idx % (FOUT / 4);
      float4 w = *(const float4*)(W + r * FOUT + c4 * 4);
      float* p = &WS[r * PADW + c4 * 4];
      p[0] = w.x; p[1] = w.y; p[2] = w.z; p[3] = w.w;
    }
    for (int idx = tid; idx < 64 * 16; idx += blockDim.x) {
      int r = idx / 16, c4 = idx % 16;
      int n = n_base + r;
      float4 t = (n < N) ? *(const float4*)(Tx + (size_t)n * 64 + c4 * 4)
                         : make_float4(0.f, 0.f, 0.f, 0.f);
      if (pass == 0 && abA) {
        float4 a4 = *(const float4*)(abA + c4 * 4);
        float4 b4 = *(const float4*)(abA + 64 + c4 * 4);
        t.x = t.x * a4.x + b4.x;
        t.y = t.y * a4.y + b4.y;
        t.z = t.z * a4.z + b4.z;
        t.w = t.w * a4.w + b4.w;
      }
      TxT[(c4 * 4 + 0) * PADT + r] = t.x;
      TxT[(c4 * 4 + 1) * PADT + r] = t.y;
      TxT[(c4 * 4 + 2) * PADT + r] = t.z;
      TxT[(c4 * 4 + 3) * PADT + r] = t.w;
    }
    __syncthreads();
#pragma unroll 8
    for (int i = 0; i < 64; i++) {
      float4 tx = *(const float4*)(&TxT[i * PADT + n0]);
      float4 w = *(const float4*)(&WS[i * PADW + j0]);
      acc[0][0] += tx.x * w.x; acc[0][1] += tx.x * w.y; acc[0][2] += tx.x * w.z; acc[0][3] += tx.x * w.w;
      acc[1][0] += tx.y * w.x; acc[1][1] += tx.y * w.y; acc[1][2] += tx.y * w.z; acc[1][3] += tx.y * w.w;
      acc[2][0] += tx.z * w.x; acc[2][1] += tx.z * w.y; acc[2][2] += tx.z * w.z; acc[2][3] += tx.z * w.w;
      acc[3][0] += tx.w * w.x; acc[3][1] += tx.w * w.y; acc[3][2] += tx.w * w.z; acc[3][3] += tx.w * w.w;
    }
  }

  for (int a = 0; a < 4; a++) {
    int n = n_base + n0 + a;
    if (n < N)
      *(float4*)(H + (size_t)n * FOUT + j0) = make_float4(acc[a][0], acc[a][1], acc[a][2], acc[a][3]);
  }
}

// ---------------- simple combine for Fin=3 (layer 1) ----------------
__global__ void k_combine3(float* __restrict__ H, const float* __restrict__ TxA,
                           const float* __restrict__ WA, const float* __restrict__ TxB,
                           const float* __restrict__ WB, const float* __restrict__ bias,
                           int N, int mode) {
  __shared__ float wa[3 * 64], wb[3 * 64];
  int tid = threadIdx.x;
  if (tid < 192) wa[tid] = WA[tid];
  if (TxB && tid < 192) wb[tid] = WB[tid];
  __syncthreads();
  int n = blockIdx.x * 4 + tid / 64;
  int j = tid % 64;
  if (n >= N) return;
  float acc = mode ? H[n * 64 + j] : bias[j];
  for (int i = 0; i < 3; i++) acc += TxA[n * 3 + i] * wa[i * 64 + j];
  if (TxB) for (int i = 0; i < 3; i++) acc += TxB[n * 3 + i] * wb[i * 64 + j];
  H[n * 64 + j] = acc;
}

// ---------------- LeakyReLU + BN stats (float4, per-block partials) ----------------
#define BN_GRID 400
__global__ void k_bnstats(float* __restrict__ H, float* __restrict__ gpart, int N) {
  __shared__ float red[256 * 8];
  int t = threadIdx.x;
  int f4 = t & 15, r = t >> 4;
  float4* H4 = (float4*)H;
  float s0 = 0.f, s1 = 0.f, s2 = 0.f, s3 = 0.f;
  float q0 = 0.f, q1 = 0.f, q2 = 0.f, q3 = 0.f;
  for (int n = blockIdx.x * 16 + r; n < N; n += BN_GRID * 16) {
    float4 v = H4[(size_t)n * 16 + f4];
    v.x = v.x >= 0.f ? v.x : 0.01f * v.x;
    v.y = v.y >= 0.f ? v.y : 0.01f * v.y;
    v.z = v.z >= 0.f ? v.z : 0.01f * v.z;
    v.w = v.w >= 0.f ? v.w : 0.01f * v.w;
    H4[(size_t)n * 16 + f4] = v;
    s0 += v.x; s1 += v.y; s2 += v.z; s3 += v.w;
    q0 += v.x * v.x; q1 += v.y * v.y; q2 += v.z * v.z; q3 += v.w * v.w;
  }
  float* rp = &red[t * 8];
  rp[0] = s0; rp[1] = s1; rp[2] = s2; rp[3] = s3;
  rp[4] = q0; rp[5] = q1; rp[6] = q2; rp[7] = q3;
  __syncthreads();
  if (t < 64) {
    int f4g = t >> 2, k = t & 3;
    float a = 0.f, b = 0.f;
    for (int rr = 0; rr < 16; rr++) {
      a += red[(rr * 16 + f4g) * 8 + k];
      b += red[(rr * 16 + f4g) * 8 + 4 + k];
    }
    gpart[blockIdx.x * 128 + t] = a;
    gpart[blockIdx.x * 128 + 64 + t] = b;
  }
}

__global__ void k_bnfinal(const float* __restrict__ gpart, const float* __restrict__ g,
                          const float* __restrict__ bt, float* __restrict__ ab, float Ninv) {
  int t = threadIdx.x;  // 128
  float s = 0.f;
  for (int b = 0; b < BN_GRID; b++) s += gpart[b * 128 + t];
  __shared__ float red[128];
  red[t] = s; __syncthreads();
  if (t < 64) {
    float mu = red[t] * Ninv;
    float var = red[64 + t] * Ninv - mu * mu;
    float a = g[t] / sqrtf(var + EPS_BN);
    ab[t] = a;
    ab[64 + t] = bt[t] - mu * a;
  }
}

// ---------------- pooling (fused row L2-normalize) ----------------
__device__ __forceinline__ unsigned fkey(float x) {
  unsigned u = __float_as_uint(x);
  return (u & 0x80000000u) ? ~u : (u | 0x80000000u);
}
__device__ __forceinline__ float fdec(unsigned u) {
  return (u & 0x80000000u) ? __uint_as_float(u & 0x7FFFFFFFu) : __uint_as_float(~u);
}

#define POOL_CHUNK 512
__global__ void k_pool2(const float* __restrict__ H, const int* __restrict__ batch,
                        float* __restrict__ psum, unsigned* __restrict__ pmax,
                        unsigned* __restrict__ pmin, float* __restrict__ pcnt, int N) {
  int f = threadIdx.x & 31;
  int sub = threadIdx.x >> 5;
  int n0 = blockIdx.x * POOL_CHUNK;
  int n1 = n0 + POOL_CHUNK; if (n1 > N) n1 = N;
  int curg = -1;
  float s = 0.f, mx = -3.4e38f, mn = 3.4e38f, cnt = 0.f;
  for (int n = n0 + sub; n < n1; n += 8) {
    int g = batch[n];
    if (g != curg) {
      if (curg >= 0) {
        atomicAdd(&psum[curg * 32 + f], s);
        atomicMax(&pmax[curg * 32 + f], fkey(mx));
        atomicMin(&pmin[curg * 32 + f], fkey(mn));
        if (f == 0) atomicAdd(&pcnt[curg], cnt);
      }
      curg = g; s = 0.f; mx = -3.4e38f; mn = 3.4e38f; cnt = 0.f;
    }
    float v = H[n * 32 + f];
    float ss = v * v;
    for (int off = 16; off; off >>= 1) ss += __shfl_xor(ss, off, 32);
    v /= fmaxf(sqrtf(ss), 1e-12f);
    s += v; mx = fmaxf(mx, v); mn = fminf(mn, v); cnt += 1.f;
  }
  if (curg >= 0) {
    atomicAdd(&psum[curg * 32 + f], s);
    atomicMax(&pmax[curg * 32 + f], fkey(mx));
    atomicMin(&pmin[curg * 32 + f], fkey(mn));
    if (f == 0) atomicAdd(&pcnt[curg], cnt);
  }
}

__global__ void k_poolfin(const float* __restrict__ psum, const unsigned* __restrict__ pmax,
                          const unsigned* __restrict__ pmin, const float* __restrict__ pcnt,
                          float* __restrict__ out) {
  int g = blockIdx.x, f = threadIdx.x;
  float s = psum[g * 32 + f];
  float c = fmaxf(pcnt[g], 1.0f);
  out[g * 128 + f] = s / c;
  out[g * 128 + 32 + f] = fdec(pmax[g * 32 + f]);
  out[g * 128 + 64 + f] = fdec(pmin[g * 32 + f]);
  out[g * 128 + 96 + f] = s;
}

// ---------------- host ----------------

extern "C" void kernel_launch(void* const* d_in, const int* in_sizes, int n_in,
                              void* d_out, int out_size, void* d_ws, size_t ws_size,
                              hipStream_t stream) {
  const float* x   = (const float*)d_in[0];
  const int*   ei  = (const int*)d_in[1];
  const int*   bat = (const int*)d_in[2];
  const float* W1  = (const float*)d_in[3];  const float* bc1 = (const float*)d_in[4];
  const float* W2  = (const float*)d_in[5];  const float* bc2 = (const float*)d_in[6];
  const float* W3  = (const float*)d_in[7];  const float* bc3 = (const float*)d_in[8];
  const float* W4  = (const float*)d_in[9];  const float* bc4 = (const float*)d_in[10];
  const float* g1  = (const float*)d_in[11]; const float* bt1 = (const float*)d_in[12];
  const float* g2  = (const float*)d_in[13]; const float* bt2 = (const float*)d_in[14];
  const float* g3  = (const float*)d_in[15]; const float* bt3 = (const float*)d_in[16];

  const int N = in_sizes[0] / 3;
  const int E = in_sizes[1] / 2;
  const int* src = ei;
  const int* dst = ei + E;
  const size_t Epad = (size_t)E + (size_t)(ROWPAD - 1) * N + 64;

  float* base = (float*)d_ws;
  size_t o = 0;
  auto alloc = [&](size_t n) -> float* {
    float* p = base + o;
    o += (n + 63) & ~(size_t)63;
    return p;
  };
  // zeroed region (contiguous from d_ws start):
  int*   cursor = (int*)alloc(N);
  float* psum   = alloc(64 * 32);
  float* pcnt   = alloc(64);
  unsigned* pmax = (unsigned*)alloc(64 * 32);
  int2*  erec  = (int2*)alloc(2 * Epad);  // zero: pad slots = {src 0, w 0}
  size_t zero_elems = o;
  // 0xFF region:
  unsigned* pmin = (unsigned*)alloc(64 * 32);
  // uninitialized (fully overwritten before read):
  float* dinv  = alloc(N);
  int*   hist  = (int*)alloc(N);
  int*   offs  = (int*)alloc(N + 1);
  int*   bsum  = (int*)alloc(256);
  int*   bbase = (int*)alloc(257);
  float* gpart = alloc(BN_GRID * 128);
  float* ab    = alloc(128);
  float* A     = alloc((size_t)N * 64);
  float* B     = alloc((size_t)N * 64);
  float* H     = alloc((size_t)N * 64);
  float* C32   = alloc((size_t)N * 32);

  hipMemsetAsync(d_ws, 0, zero_elems * sizeof(float), stream);
  hipMemsetAsync(pmin, 0xFF, 64 * 32 * sizeof(unsigned), stream);

  const int EB = (E + 255) / 256;
  const int NB = (N + 255) / 256;
  const int SB = (N + SC_CHUNK - 1) / SC_CHUNK;
  const int S  = (N + HSEG - 1) / HSEG;
  const int SP = S * HSEG;
  int* partial = (int*)A;  // alias: 2*HC*SP ints (~14.5 MB) << N*64 floats; A unused until layer 2

  k_histseg<<<dim3(S, HC, 2), 256, 0, stream>>>(src, dst, partial, E, SP);
  k_histred<<<NB, 256, 0, stream>>>(partial, dinv, hist, N, SP);
  k_scan1<<<SB, 256, 0, stream>>>(hist, bsum, N);
  k_scan2<<<1, 256, 0, stream>>>(bsum, bbase, SB);
  k_scan3<<<SB, 256, 0, stream>>>(hist, bbase, offs, N, SB);
  k_scatter<<<EB, 256, 0, stream>>>(src, dst, dinv, offs, cursor, erec, E);

  const int PB64 = (N * 64 + 255) / 256;
  const int TB = (N + 63) / 64;
  const int4* erec4 = (const int4*)erec;

  // ---- layer 1: Fin=3 -> 64 ----
  {
    const float* W = W1;
    k_prop3<<<NB, 256, 0, stream>>>(x, nullptr, B, offs, erec4, N, 0);
    k_combine3<<<(N + 3) / 4, 256, 0, stream>>>(H, x, W + 0 * 192, B, W + 1 * 192, bc1, N, 0);
    k_prop3<<<NB, 256, 0, stream>>>(B, x, A, offs, erec4, N, 1);
    k_combine3<<<(N + 3) / 4, 256, 0, stream>>>(H, A, W + 2 * 192, nullptr, nullptr, nullptr, N, 1);
    k_prop3<<<NB, 256, 0, stream>>>(A, B, B, offs, erec4, N, 1);
    k_combine3<<<(N + 3) / 4, 256, 0, stream>>>(H, B, W + 3 * 192, nullptr, nullptr, nullptr, N, 1);
    k_bnstats<<<BN_GRID, 256, 0, stream>>>(H, gpart, N);
    k_bnfinal<<<1, 128, 0, stream>>>(gpart, g1, bt1, ab, 1.0f / N);
  }

  // ---- layers 2 & 3: 64 -> 64 (Tx0 = ab∘H virtual; combine in-place on H) ----
  const float* Ws[2] = {W2, W3};
  const float* bs[2] = {bc2, bc3};
  const float* gs[2] = {g2, g3};
  const float* bts[2] = {bt2, bt3};
  for (int L = 0; L < 2; L++) {
    const float* W = Ws[L];
    k_prop64<<<PB64, 256, 0, stream>>>(H, ab, nullptr, nullptr, B, offs, erec4, N, 0);
    k_prop64<<<PB64, 256, 0, stream>>>(B, nullptr, H, ab, A, offs, erec4, N, 1);
    k_combine_t<64><<<TB, 256, 0, stream>>>(H, H, W + 0 * 4096, B, W + 1 * 4096, bs[L], ab, N, 0);
    k_combine_t<64><<<TB, 256, 0, stream>>>(H, A, W + 2 * 4096, nullptr, nullptr, nullptr, nullptr, N, 1);
    k_prop64<<<PB64, 256, 0, stream>>>(A, nullptr, B, nullptr, B, offs, erec4, N, 1);
    k_combine_t<64><<<TB, 256, 0, stream>>>(H, B, W + 3 * 4096, nullptr, nullptr, nullptr, nullptr, N, 1);
    k_bnstats<<<BN_GRID, 256, 0, stream>>>(H, gpart, N);
    k_bnfinal<<<1, 128, 0, stream>>>(gpart, gs[L], bts[L], ab, 1.0f / N);
  }

  // ---- layer 4: 64 -> 32 (output C32) ----
  {
    const float* W = W4;
    k_prop64<<<PB64, 256, 0, stream>>>(H, ab, nullptr, nullptr, B, offs, erec4, N, 0);
    k_prop64<<<PB64, 256, 0, stream>>>(B, nullptr, H, ab, A, offs, erec4, N, 1);
    k_combine_t<32><<<TB, 128, 0, stream>>>(C32, H, W + 0 * 2048, B, W + 1 * 2048, bc4, ab, N, 0);
    k_combine_t<32><<<TB, 128, 0, stream>>>(C32, A, W + 2 * 2048, nullptr, nullptr, nullptr, nullptr, N, 1);
    k_prop64<<<PB64, 256, 0, stream>>>(A, nullptr, B, nullptr, B, offs, erec4, N, 1);
    k_combine_t<32><<<TB, 128, 0, stream>>>(C32, B, W + 3 * 2048, nullptr, nullptr, nullptr, nullptr, N, 1);
  }

  // ---- pool (L2-normalize fused) ----
  k_pool2<<<(N + POOL_CHUNK - 1) / POOL_CHUNK, 256, 0, stream>>>(C32, bat, psum, pmax, pmin, pcnt, N);
  k_poolfin<<<64, 32, 0, stream>>>(psum, pmax, pmin, pcnt, (float*)d_out);
}

// Round 7
// 1030.204 us; speedup vs baseline: 3.5323x; 1.2143x over previous
//
#include <hip/hip_runtime.h>

#define EPS_BN 1e-5f
#define ROWPAD 8    // CSR rows padded to multiple of 8 edges (src=0,w=0 filler)
#define HSEG 16384  // histogram bins per segment (packed u16 -> 32 KB LDS)
#define HC 32       // histogram edge-chunks

typedef unsigned short u16;

__device__ __forceinline__ float b2f(u16 u) {
  return __uint_as_float(((unsigned)u) << 16);
}
__device__ __forceinline__ u16 f2b(float f) {  // RTNE
  unsigned u = __float_as_uint(f);
  u += 0x7fffu + ((u >> 16) & 1u);
  return (u16)(u >> 16);
}

// ---------------- preprocessing: packed-u16 LDS segmented histograms ----------------
// grid (S, HC, 2): z=0 counts src, z=1 counts dst; partial is u16[2][HC][SP]
__global__ void k_histseg(const int* __restrict__ src, const int* __restrict__ dst,
                          unsigned* __restrict__ partial, int E, int SP) {
  __shared__ unsigned bins[HSEG / 2];
  int s = blockIdx.x, c = blockIdx.y, z = blockIdx.z;
  int t = threadIdx.x;
  for (int i = t; i < HSEG / 2; i += 256) bins[i] = 0;
  __syncthreads();
  const int* keys = z ? dst : src;
  int lo = s * HSEG;
  int ck = (E + HC - 1) / HC;
  int e0 = c * ck, e1 = e0 + ck; if (e1 > E) e1 = E;
  for (int e = e0 + t; e < e1; e += 256) {
    int k = keys[e] - lo;
    if ((unsigned)k < (unsigned)HSEG)
      atomicAdd(&bins[k >> 1], 1u << ((k & 1) * 16));
  }
  __syncthreads();
  unsigned* out = partial + (size_t)(z * HC + c) * (SP >> 1) + (lo >> 1);
  for (int i = t; i < HSEG / 2; i += 256) out[i] = bins[i];
}

// reduce u16 partials -> dinv (float) + hist (int)
__global__ void k_histred(const u16* __restrict__ partial, float* __restrict__ dinv,
                          int* __restrict__ hist, int N, int SP) {
  int n = blockIdx.x * 256 + threadIdx.x;
  if (n >= N) return;
  int a = 0, b = 0;
  for (int c = 0; c < HC; c++) a += partial[(size_t)c * SP + n];
  for (int c = 0; c < HC; c++) b += partial[(size_t)(HC + c) * SP + n];
  dinv[n] = a > 0 ? rsqrtf((float)a) : 0.f;
  hist[n] = b;
}

// ---- hierarchical scan over PADDED counts ----
#define SC_CHUNK 400

__device__ __forceinline__ int lds_incl_scan256(int* lds, int t, int v) {
  lds[t] = v; __syncthreads();
  for (int off = 1; off < 256; off <<= 1) {
    int u = (t >= off) ? lds[t - off] : 0;
    __syncthreads();
    lds[t] += u;
    __syncthreads();
  }
  return lds[t];
}

__device__ __forceinline__ int padcnt(int h) { return (h + (ROWPAD - 1)) & ~(ROWPAD - 1); }

__global__ void k_scan1(const int* __restrict__ hist, int* __restrict__ bsum, int N) {
  __shared__ int lds[256];
  int b = blockIdx.x, t = threadIdx.x;
  int lo = b * SC_CHUNK;
  int hi = lo + SC_CHUNK; if (hi > N) hi = N;
  int i0 = lo + t * 2;
  int s = 0;
  if (i0 < hi) s += padcnt(hist[i0]);
  if (i0 + 1 < hi) s += padcnt(hist[i0 + 1]);
  int incl = lds_incl_scan256(lds, t, s);
  if (t == 255) bsum[b] = incl;
}

__global__ void k_scan2(const int* __restrict__ bsum, int* __restrict__ bbase, int nb) {
  __shared__ int lds[256];
  int t = threadIdx.x;
  int v = (t < nb) ? bsum[t] : 0;
  int incl = lds_incl_scan256(lds, t, v);
  if (t < nb) bbase[t] = incl - v;
  if (t == nb - 1) bbase[nb] = incl;
}

__global__ void k_scan3(const int* __restrict__ hist, const int* __restrict__ bbase,
                        int* __restrict__ offs, int N, int nb) {
  __shared__ int lds[256];
  int b = blockIdx.x, t = threadIdx.x;
  int lo = b * SC_CHUNK;
  int hi = lo + SC_CHUNK; if (hi > N) hi = N;
  int i0 = lo + t * 2;
  int h0 = (i0 < hi) ? padcnt(hist[i0]) : 0;
  int h1 = (i0 + 1 < hi) ? padcnt(hist[i0 + 1]) : 0;
  int s = h0 + h1;
  int incl = lds_incl_scan256(lds, t, s);
  int run = bbase[b] + incl - s;
  if (i0 < hi) offs[i0] = run;
  if (i0 + 1 < hi) offs[i0 + 1] = run + h0;
  if (b == 0 && t == 0) offs[N] = bbase[nb];
}

__global__ void k_scatter(const int* __restrict__ src, const int* __restrict__ dst,
                          const float* __restrict__ dinv, const int* __restrict__ offs,
                          int* __restrict__ cursor, int2* __restrict__ erec, int E) {
  int e = blockIdx.x * 256 + threadIdx.x;
  if (e >= E) return;
  int s = src[e], d = dst[e];
  int pos = offs[d] + atomicAdd(&cursor[d], 1);
  int2 r;
  r.x = s;
  r.y = __float_as_int(-dinv[s] * dinv[d]);
  erec[pos] = r;
}

// ---------------- propagation (padded CSR, bf16 feature table, f32 accum) ----------------
__global__ void k_prop64b(const u16* __restrict__ gf, const float* __restrict__ gab,
                          const u16* __restrict__ oldv, const float* __restrict__ oab,
                          u16* __restrict__ outv, const int* __restrict__ offs,
                          const int4* __restrict__ erec4, int N, int recur) {
  int wid = (blockIdx.x * 256 + threadIdx.x) >> 6;
  int lane = threadIdx.x & 63;
  if (wid >= N) return;
  int q = offs[wid] >> 1, qe = offs[wid + 1] >> 1;  // int4 units (2 records each)
  float acc = 0.f, sw = 0.f;
  for (; q + 8 <= qe; q += 8) {  // 16 records
    int4 m[8];
#pragma unroll
    for (int j = 0; j < 8; j++) m[j] = erec4[q + j];
    u16 g[16];
#pragma unroll
    for (int j = 0; j < 8; j++) {
      g[2 * j]     = gf[(size_t)m[j].x * 64 + lane];
      g[2 * j + 1] = gf[(size_t)m[j].z * 64 + lane];
    }
#pragma unroll
    for (int j = 0; j < 8; j++) {
      float w0 = __int_as_float(m[j].y), w1 = __int_as_float(m[j].w);
      acc += w0 * b2f(g[2 * j]) + w1 * b2f(g[2 * j + 1]);
      sw += w0 + w1;
    }
  }
  if (q < qe) {  // exactly 8 records
    int4 m[4];
#pragma unroll
    for (int j = 0; j < 4; j++) m[j] = erec4[q + j];
    u16 g[8];
#pragma unroll
    for (int j = 0; j < 4; j++) {
      g[2 * j]     = gf[(size_t)m[j].x * 64 + lane];
      g[2 * j + 1] = gf[(size_t)m[j].z * 64 + lane];
    }
#pragma unroll
    for (int j = 0; j < 4; j++) {
      float w0 = __int_as_float(m[j].y), w1 = __int_as_float(m[j].w);
      acc += w0 * b2f(g[2 * j]) + w1 * b2f(g[2 * j + 1]);
      sw += w0 + w1;
    }
  }
  float res = acc;
  if (gab) res = gab[lane] * acc + gab[64 + lane] * sw;
  int idx = wid * 64 + lane;
  if (recur) {
    float o = b2f(oldv[idx]);
    if (oab) o = oab[lane] * o + oab[64 + lane];
    res = 2.f * res - o;
  }
  outv[idx] = f2b(res);
}

// F=3 f32 variant (layer 1)
__global__ void k_prop3(const float* __restrict__ gf, const float* __restrict__ oldv,
                        float* __restrict__ outv, const int* __restrict__ offs,
                        const int4* __restrict__ erec4, int N, int recur) {
  int n = blockIdx.x * 256 + threadIdx.x;
  if (n >= N) return;
  int q = offs[n] >> 1, qe = offs[n + 1] >> 1;
  float a0 = 0.f, a1 = 0.f, a2 = 0.f;
  for (; q < qe; q += 4) {
    int4 m[4];
#pragma unroll
    for (int j = 0; j < 4; j++) m[j] = erec4[q + j];
#pragma unroll
    for (int j = 0; j < 4; j++) {
      float w0 = __int_as_float(m[j].y), w1 = __int_as_float(m[j].w);
      int s0 = m[j].x, s1 = m[j].z;
      a0 += w0 * gf[s0 * 3 + 0] + w1 * gf[s1 * 3 + 0];
      a1 += w0 * gf[s0 * 3 + 1] + w1 * gf[s1 * 3 + 1];
      a2 += w0 * gf[s0 * 3 + 2] + w1 * gf[s1 * 3 + 2];
    }
  }
  if (recur) {
    a0 = 2.f * a0 - oldv[n * 3 + 0];
    a1 = 2.f * a1 - oldv[n * 3 + 1];
    a2 = 2.f * a2 - oldv[n * 3 + 2];
  }
  outv[n * 3 + 0] = a0;
  outv[n * 3 + 1] = a1;
  outv[n * 3 + 2] = a2;
}

// ---------------- merged 4-term combine: out = bias + Σp Tp@Wp ----------------
// T0..T3 bf16 node features [N][64]; ab applied to T0 while staging.
// W contiguous [4][64][FOUT]. In-place safe vs T0 (block-tile-local).
template <int FOUT, bool OUTBF>
__global__ void k_combine4(void* outp, const u16* T0, const float* __restrict__ ab,
                           const u16* __restrict__ T1, const u16* __restrict__ T2,
                           const u16* __restrict__ T3, const float* __restrict__ W,
                           const float* __restrict__ bias, int N) {
  constexpr int PADT = 68;
  constexpr int PADW = FOUT + 4;
  __shared__ float TxT[64 * PADT];
  __shared__ float WS[64 * PADW];
  int tid = threadIdx.x;
  int n_base = blockIdx.x * 64;
  int tj = tid % (FOUT / 4);
  int tn = tid / (FOUT / 4);  // 0..15
  int j0 = tj * 4, n0 = tn * 4;

  float acc[4][4];
  {
    float4 b = *(const float4*)(bias + j0);
    for (int a = 0; a < 4; a++) { acc[a][0] = b.x; acc[a][1] = b.y; acc[a][2] = b.z; acc[a][3] = b.w; }
  }

  const u16* Ts[4] = {T0, T1, T2, T3};
  for (int p = 0; p < 4; p++) {
    if (p) __syncthreads();
    // stage W_p [64 x FOUT]
    for (int idx = tid; idx < 64 * FOUT / 4; idx += blockDim.x) {
      int r = idx / (FOUT / 4), c4 = idx % (FOUT / 4);
      float4 w = *(const float4*)(W + p * 64 * FOUT + r * FOUT + c4 * 4);
      float* pp = &WS[r * PADW + c4 * 4];
      pp[0] = w.x; pp[1] = w.y; pp[2] = w.z; pp[3] = w.w;
    }
    // stage T_p transposed [64 feats][64 nodes], bf16 -> f32
    for (int idx = tid; idx < 64 * 16; idx += blockDim.x) {
      int r = idx / 16, c4 = idx % 16;
      int n = n_base + r;
      float t0 = 0.f, t1 = 0.f, t2 = 0.f, t3 = 0.f;
      if (n < N) {
        ushort4 u = *(const ushort4*)(Ts[p] + (size_t)n * 64 + c4 * 4);
        t0 = b2f(u.x); t1 = b2f(u.y); t2 = b2f(u.z); t3 = b2f(u.w);
      }
      if (p == 0 && ab) {
        float4 a4 = *(const float4*)(ab + c4 * 4);
        float4 b4 = *(const float4*)(ab + 64 + c4 * 4);
        t0 = t0 * a4.x + b4.x;
        t1 = t1 * a4.y + b4.y;
        t2 = t2 * a4.z + b4.z;
        t3 = t3 * a4.w + b4.w;
      }
      TxT[(c4 * 4 + 0) * PADT + r] = t0;
      TxT[(c4 * 4 + 1) * PADT + r] = t1;
      TxT[(c4 * 4 + 2) * PADT + r] = t2;
      TxT[(c4 * 4 + 3) * PADT + r] = t3;
    }
    __syncthreads();
#pragma unroll 8
    for (int i = 0; i < 64; i++) {
      float4 tx = *(const float4*)(&TxT[i * PADT + n0]);
      float4 w = *(const float4*)(&WS[i * PADW + j0]);
      acc[0][0] += tx.x * w.x; acc[0][1] += tx.x * w.y; acc[0][2] += tx.x * w.z; acc[0][3] += tx.x * w.w;
      acc[1][0] += tx.y * w.x; acc[1][1] += tx.y * w.y; acc[1][2] += tx.y * w.z; acc[1][3] += tx.y * w.w;
      acc[2][0] += tx.z * w.x; acc[2][1] += tx.z * w.y; acc[2][2] += tx.z * w.z; acc[2][3] += tx.z * w.w;
      acc[3][0] += tx.w * w.x; acc[3][1] += tx.w * w.y; acc[3][2] += tx.w * w.z; acc[3][3] += tx.w * w.w;
    }
  }

  for (int a = 0; a < 4; a++) {
    int n = n_base + n0 + a;
    if (n < N) {
      if (OUTBF) {
        ushort4 o;
        o.x = f2b(acc[a][0]); o.y = f2b(acc[a][1]); o.z = f2b(acc[a][2]); o.w = f2b(acc[a][3]);
        *(ushort4*)((u16*)outp + (size_t)n * FOUT + j0) = o;
      } else {
        *(float4*)((float*)outp + (size_t)n * FOUT + j0) =
            make_float4(acc[a][0], acc[a][1], acc[a][2], acc[a][3]);
      }
    }
  }
}

// ---------------- merged layer-1 combine (Fin=3, f32 in, bf16 out) ----------------
__global__ void k_combine1(u16* __restrict__ H, const float* __restrict__ x,
                           const float* __restrict__ t1, const float* __restrict__ t2,
                           const float* __restrict__ t3, const float* __restrict__ W,
                           const float* __restrict__ bias, int N) {
  __shared__ float ws[768];  // [4][3][64]
  int tid = threadIdx.x;
  for (int i = tid; i < 768; i += 256) ws[i] = W[i];
  __syncthreads();
  int n = blockIdx.x * 4 + tid / 64;
  int j = tid % 64;
  if (n >= N) return;
  float acc = bias[j];
  const float* xs[4] = {x, t1, t2, t3};
#pragma unroll
  for (int p = 0; p < 4; p++)
#pragma unroll
    for (int i = 0; i < 3; i++)
      acc += xs[p][n * 3 + i] * ws[p * 192 + i * 64 + j];
  H[(size_t)n * 64 + j] = f2b(acc);
}

// ---------------- LeakyReLU + BN stats (bf16 in-place, f32 partials) ----------------
#define BN_GRID 400
__global__ void k_bnstats(u16* __restrict__ H, float* __restrict__ gpart, int N) {
  __shared__ float red[256 * 8];
  int t = threadIdx.x;
  int f4 = t & 15, r = t >> 4;
  float s0 = 0.f, s1 = 0.f, s2 = 0.f, s3 = 0.f;
  float q0 = 0.f, q1 = 0.f, q2 = 0.f, q3 = 0.f;
  for (int n = blockIdx.x * 16 + r; n < N; n += BN_GRID * 16) {
    ushort4 u = *(ushort4*)(H + (size_t)n * 64 + f4 * 4);
    float vx = b2f(u.x), vy = b2f(u.y), vz = b2f(u.z), vw = b2f(u.w);
    vx = vx >= 0.f ? vx : 0.01f * vx;
    vy = vy >= 0.f ? vy : 0.01f * vy;
    vz = vz >= 0.f ? vz : 0.01f * vz;
    vw = vw >= 0.f ? vw : 0.01f * vw;
    ushort4 o; o.x = f2b(vx); o.y = f2b(vy); o.z = f2b(vz); o.w = f2b(vw);
    *(ushort4*)(H + (size_t)n * 64 + f4 * 4) = o;
    s0 += vx; s1 += vy; s2 += vz; s3 += vw;
    q0 += vx * vx; q1 += vy * vy; q2 += vz * vz; q3 += vw * vw;
  }
  float* rp = &red[t * 8];
  rp[0] = s0; rp[1] = s1; rp[2] = s2; rp[3] = s3;
  rp[4] = q0; rp[5] = q1; rp[6] = q2; rp[7] = q3;
  __syncthreads();
  if (t < 64) {
    int f4g = t >> 2, k = t & 3;
    float a = 0.f, b = 0.f;
    for (int rr = 0; rr < 16; rr++) {
      a += red[(rr * 16 + f4g) * 8 + k];
      b += red[(rr * 16 + f4g) * 8 + 4 + k];
    }
    gpart[blockIdx.x * 128 + t] = a;
    gpart[blockIdx.x * 128 + 64 + t] = b;
  }
}

__global__ void k_bnfinal(const float* __restrict__ gpart, const float* __restrict__ g,
                          const float* __restrict__ bt, float* __restrict__ ab, float Ninv) {
  int t = threadIdx.x;  // 128
  float s = 0.f;
  for (int b = 0; b < BN_GRID; b++) s += gpart[b * 128 + t];
  __shared__ float red[128];
  red[t] = s; __syncthreads();
  if (t < 64) {
    float mu = red[t] * Ninv;
    float var = red[64 + t] * Ninv - mu * mu;
    float a = g[t] / sqrtf(var + EPS_BN);
    ab[t] = a;
    ab[64 + t] = bt[t] - mu * a;
  }
}

// ---------------- pooling (fused row L2-normalize) ----------------
__device__ __forceinline__ unsigned fkey(float x) {
  unsigned u = __float_as_uint(x);
  return (u & 0x80000000u) ? ~u : (u | 0x80000000u);
}
__device__ __forceinline__ float fdec(unsigned u) {
  return (u & 0x80000000u) ? __uint_as_float(u & 0x7FFFFFFFu) : __uint_as_float(~u);
}

#define POOL_CHUNK 512
__global__ void k_pool2(const float* __restrict__ H, const int* __restrict__ batch,
                        float* __restrict__ psum, unsigned* __restrict__ pmax,
                        unsigned* __restrict__ pmin, float* __restrict__ pcnt, int N) {
  int f = threadIdx.x & 31;
  int sub = threadIdx.x >> 5;
  int n0 = blockIdx.x * POOL_CHUNK;
  int n1 = n0 + POOL_CHUNK; if (n1 > N) n1 = N;
  int curg = -1;
  float s = 0.f, mx = -3.4e38f, mn = 3.4e38f, cnt = 0.f;
  for (int n = n0 + sub; n < n1; n += 8) {
    int g = batch[n];
    if (g != curg) {
      if (curg >= 0) {
        atomicAdd(&psum[curg * 32 + f], s);
        atomicMax(&pmax[curg * 32 + f], fkey(mx));
        atomicMin(&pmin[curg * 32 + f], fkey(mn));
        if (f == 0) atomicAdd(&pcnt[curg], cnt);
      }
      curg = g; s = 0.f; mx = -3.4e38f; mn = 3.4e38f; cnt = 0.f;
    }
    float v = H[n * 32 + f];
    float ss = v * v;
    for (int off = 16; off; off >>= 1) ss += __shfl_xor(ss, off, 32);
    v /= fmaxf(sqrtf(ss), 1e-12f);
    s += v; mx = fmaxf(mx, v); mn = fminf(mn, v); cnt += 1.f;
  }
  if (curg >= 0) {
    atomicAdd(&psum[curg * 32 + f], s);
    atomicMax(&pmax[curg * 32 + f], fkey(mx));
    atomicMin(&pmin[curg * 32 + f], fkey(mn));
    if (f == 0) atomicAdd(&pcnt[curg], cnt);
  }
}

__global__ void k_poolfin(const float* __restrict__ psum, const unsigned* __restrict__ pmax,
                          const unsigned* __restrict__ pmin, const float* __restrict__ pcnt,
                          float* __restrict__ out) {
  int g = blockIdx.x, f = threadIdx.x;
  float s = psum[g * 32 + f];
  float c = fmaxf(pcnt[g], 1.0f);
  out[g * 128 + f] = s / c;
  out[g * 128 + 32 + f] = fdec(pmax[g * 32 + f]);
  out[g * 128 + 64 + f] = fdec(pmin[g * 32 + f]);
  out[g * 128 + 96 + f] = s;
}

// ---------------- host ----------------

extern "C" void kernel_launch(void* const* d_in, const int* in_sizes, int n_in,
                              void* d_out, int out_size, void* d_ws, size_t ws_size,
                              hipStream_t stream) {
  const float* x   = (const float*)d_in[0];
  const int*   ei  = (const int*)d_in[1];
  const int*   bat = (const int*)d_in[2];
  const float* W1  = (const float*)d_in[3];  const float* bc1 = (const float*)d_in[4];
  const float* W2  = (const float*)d_in[5];  const float* bc2 = (const float*)d_in[6];
  const float* W3  = (const float*)d_in[7];  const float* bc3 = (const float*)d_in[8];
  const float* W4  = (const float*)d_in[9];  const float* bc4 = (const float*)d_in[10];
  const float* g1  = (const float*)d_in[11]; const float* bt1 = (const float*)d_in[12];
  const float* g2  = (const float*)d_in[13]; const float* bt2 = (const float*)d_in[14];
  const float* g3  = (const float*)d_in[15]; const float* bt3 = (const float*)d_in[16];

  const int N = in_sizes[0] / 3;
  const int E = in_sizes[1] / 2;
  const int* src = ei;
  const int* dst = ei + E;
  const size_t Epad = (size_t)E + (size_t)(ROWPAD - 1) * N + 64;

  float* base = (float*)d_ws;
  size_t o = 0;
  auto alloc = [&](size_t n) -> float* {
    float* p = base + o;
    o += (n + 63) & ~(size_t)63;
    return p;
  };
  // zeroed region (contiguous from d_ws start):
  int*   cursor = (int*)alloc(N);
  float* psum   = alloc(64 * 32);
  float* pcnt   = alloc(64);
  unsigned* pmax = (unsigned*)alloc(64 * 32);
  int2*  erec  = (int2*)alloc(2 * Epad);  // zero: pad slots = {src 0, w 0}
  size_t zero_elems = o;
  // 0xFF region:
  unsigned* pmin = (unsigned*)alloc(64 * 32);
  // uninitialized (fully overwritten before read):
  float* dinv  = alloc(N);
  int*   hist  = (int*)alloc(N);
  int*   offs  = (int*)alloc(N + 1);
  int*   bsum  = (int*)alloc(256);
  int*   bbase = (int*)alloc(257);
  float* gpart = alloc(BN_GRID * 128);
  float* ab    = alloc(128);
  float* t1f   = alloc(3 * (size_t)N);
  float* t2f   = alloc(3 * (size_t)N);
  float* t3f   = alloc(3 * (size_t)N);
  u16*   T0    = (u16*)alloc((size_t)N * 32);  // bf16 [N][64]
  u16*   T1    = (u16*)alloc((size_t)N * 32);
  u16*   T2    = (u16*)alloc((size_t)N * 32);
  u16*   T3    = (u16*)alloc((size_t)N * 32);
  float* C32   = alloc((size_t)N * 32);

  hipMemsetAsync(d_ws, 0, zero_elems * sizeof(float), stream);
  hipMemsetAsync(pmin, 0xFF, 64 * 32 * sizeof(unsigned), stream);

  const int EB = (E + 255) / 256;
  const int NB = (N + 255) / 256;
  const int SB = (N + SC_CHUNK - 1) / SC_CHUNK;
  const int S  = (N + HSEG - 1) / HSEG;
  const int SP = S * HSEG;
  unsigned* partial = (unsigned*)T0;  // alias: 2*HC*SP u16 (~14.7 MB) fits in T0+T1 (25.6 MB)

  k_histseg<<<dim3(S, HC, 2), 256, 0, stream>>>(src, dst, partial, E, SP);
  k_histred<<<NB, 256, 0, stream>>>((const u16*)partial, dinv, hist, N, SP);
  k_scan1<<<SB, 256, 0, stream>>>(hist, bsum, N);
  k_scan2<<<1, 256, 0, stream>>>(bsum, bbase, SB);
  k_scan3<<<SB, 256, 0, stream>>>(hist, bbase, offs, N, SB);
  k_scatter<<<EB, 256, 0, stream>>>(src, dst, dinv, offs, cursor, erec, E);

  const int PB64 = (N * 64 + 255) / 256;
  const int TB = (N + 63) / 64;
  const int4* erec4 = (const int4*)erec;

  // ---- layer 1: Fin=3 -> 64 (f32 props, merged combine -> bf16 H) ----
  k_prop3<<<NB, 256, 0, stream>>>(x, nullptr, t1f, offs, erec4, N, 0);
  k_prop3<<<NB, 256, 0, stream>>>(t1f, x, t2f, offs, erec4, N, 1);
  k_prop3<<<NB, 256, 0, stream>>>(t2f, t1f, t3f, offs, erec4, N, 1);
  k_combine1<<<(N + 3) / 4, 256, 0, stream>>>(T0, x, t1f, t2f, t3f, W1, bc1, N);
  k_bnstats<<<BN_GRID, 256, 0, stream>>>(T0, gpart, N);
  k_bnfinal<<<1, 128, 0, stream>>>(gpart, g1, bt1, ab, 1.0f / N);

  // ---- layers 2 & 3: 64 -> 64 ----
  const float* Ws[2] = {W2, W3};
  const float* bs[2] = {bc2, bc3};
  const float* gs[2] = {g2, g3};
  const float* bts[2] = {bt2, bt3};
  for (int L = 0; L < 2; L++) {
    const float* W = Ws[L];
    k_prop64b<<<PB64, 256, 0, stream>>>(T0, ab, nullptr, nullptr, T1, offs, erec4, N, 0);
    k_prop64b<<<PB64, 256, 0, stream>>>(T1, nullptr, T0, ab, T2, offs, erec4, N, 1);
    k_prop64b<<<PB64, 256, 0, stream>>>(T2, nullptr, T1, nullptr, T3, offs, erec4, N, 1);
    k_combine4<64, true><<<TB, 256, 0, stream>>>(T0, T0, ab, T1, T2, T3, W, bs[L], N);
    k_bnstats<<<BN_GRID, 256, 0, stream>>>(T0, gpart, N);
    k_bnfinal<<<1, 128, 0, stream>>>(gpart, gs[L], bts[L], ab, 1.0f / N);
  }

  // ---- layer 4: 64 -> 32 (f32 out C32) ----
  k_prop64b<<<PB64, 256, 0, stream>>>(T0, ab, nullptr, nullptr, T1, offs, erec4, N, 0);
  k_prop64b<<<PB64, 256, 0, stream>>>(T1, nullptr, T0, ab, T2, offs, erec4, N, 1);
  k_prop64b<<<PB64, 256, 0, stream>>>(T2, nullptr, T1, nullptr, T3, offs, erec4, N, 1);
  k_combine4<32, false><<<TB, 128, 0, stream>>>(C32, T0, ab, T1, T2, T3, W4, bc4, N);

  // ---- pool (L2-normalize fused) ----
  k_pool2<<<(N + POOL_CHUNK - 1) / POOL_CHUNK, 256, 0, stream>>>(C32, bat, psum, pmax, pmin, pcnt, N);
  k_poolfin<<<64, 32, 0, stream>>>(psum, pmax, pmin, pcnt, (float*)d_out);
}